// Round 5
// baseline (390.186 us; speedup 1.0000x reference)
//
#include <hip/hip_runtime.h>
#include <hip/hip_bf16.h>

// ---------------------------------------------------------------------------
// GCN forward on MI355X — round 18.
// R17 post-mortem: bucketA WRITE 52->35.5MB as predicted but dur flat (50us)
// -> stores weren't the limiter; bucketA parked (3 different structures all
// floor ~50us, no pipe >21%). NEW co-bottleneck surfaced: dense_kernel 50us,
// VALU 42%, occupancy 22% -> single serial FMA chain (4-cyc dep latency =
// 25% issue/wave) x 1.75 waves/SIMD = 44% VALU, matches. Fix: 4 independent
// accumulator chains (round-robin dwords), 4x uint4 row loads, 16 rows/wave
// (2x grid). Predicted dense 50 -> ~12-16us. Everything else unchanged.
// ---------------------------------------------------------------------------

#define HID 64
#define LAB 40
#define RSH 9          // 512 rows per bucket
#define KMAX 512       // max buckets (runtime K = 391)
#define TILE_A 7168    // elements per tile block (1024 threads x 7)
#define EPT 7          // elements per thread in bucketA/histB

__device__ __forceinline__ float loadF(const void* p, size_t i, int bf16) {
    if (bf16) return __bfloat162float(((const __hip_bfloat16*)p)[i]);
    return ((const float*)p)[i];
}

__device__ __forceinline__ int loadI(const void* p, size_t i, int i64) {
    if (i64) return (int)(((const long long*)p)[i]);
    return ((const int*)p)[i];
}

// packed bf16x2 helpers
__device__ __forceinline__ float bflo(unsigned v) { return __uint_as_float(v << 16); }
__device__ __forceinline__ float bfhi(unsigned v) { return __uint_as_float(v & 0xFFFF0000u); }
__device__ __forceinline__ unsigned bfr16(float x) {
    unsigned u = __float_as_uint(x);
    return (u + 0x7FFFu + ((u >> 16) & 1u)) >> 16;
}
__device__ __forceinline__ unsigned bfpack(float lo, float hi) {
    return bfr16(lo) | (bfr16(hi) << 16);
}

// fp8 e4m3 HW converts
__device__ __forceinline__ unsigned fp8pack4(float a, float b, float c, float d) {
    int r = __builtin_amdgcn_cvt_pk_fp8_f32(a, b, 0, false);
    r = __builtin_amdgcn_cvt_pk_fp8_f32(c, d, r, true);
    return (unsigned)r;
}

// nontemporal int2 load (keep P streams out of L2)
__device__ __forceinline__ void ntload(const int2* P, int idx, int* c, float* w) {
    long long raw = __builtin_nontemporal_load((const long long*)P + idx);
    *c = (int)(unsigned)(raw & 0xFFFFFFFFll);
    *w = __int_as_float((int)(raw >> 32));
}

// dtype probe (validated R1-R17)
__global__ void probe_kernel(const void* b1p, const void* fidxp, int* flags) {
    if (threadIdx.x == 0 && blockIdx.x == 0) {
        const unsigned short* u = (const unsigned short*)b1p;
        int bf16 = 1;
        for (int i = 0; i < 64; i += 2)
            if ((unsigned short)(u[i] & 0x7FFF) >= 0x3E80) { bf16 = 0; break; }
        const int* ip = (const int*)fidxp;
        int i64 = 1;
        for (int i = 1; i < 128; i += 2)
            if (ip[i] != 0) { i64 = 0; break; }
        flags[0] = bf16; flags[1] = i64; flags[2] = 0; flags[3] = 0;
    }
}

__global__ void zero_kernel(int4* p, int n4) {
    int i = blockIdx.x * blockDim.x + threadIdx.x;
    if (i < n4) p[i] = make_int4(0, 0, 0, 0);
}

// W1 -> packed bf16 staging: entry i = features 4i..4i+3 (uint2)
__global__ void convw1_kernel(const void* W1, uint2* w1q, const int* flags, int ne) {
    int i = blockIdx.x * blockDim.x + threadIdx.x;
    if (i < ne) {
        float f0 = loadF(W1, (size_t)4 * i,     flags[0]);
        float f1 = loadF(W1, (size_t)4 * i + 1, flags[0]);
        float f2 = loadF(W1, (size_t)4 * i + 2, flags[0]);
        float f3 = loadF(W1, (size_t)4 * i + 3, flags[0]);
        w1q[i] = make_uint2(bfpack(f0, f1), bfpack(f2, f3));
    }
}

// Bucket histogram, tiled EXACTLY like bucketA (one block per TILE_A run).
// Emits per-(bucket,block) counts cntPB[b*nblk+blk] + global totals cntB.
__global__ __launch_bounds__(1024)
void histB_kernel(const void* fidx, const void* eidx, int* cntB, int* cntPB,
                  const int* flags, int nnz, int nE, int N, int nblk) {
    __shared__ int lh[KMAX];
    if (threadIdx.x < KMAX) lh[threadIdx.x] = 0;
    __syncthreads();
    const int i64 = flags[1];
    const int nT = nnz + nE;
    const int base = blockIdx.x * TILE_A;
#pragma unroll
    for (int k = 0; k < EPT; k++) {
        int i = base + k * 1024 + threadIdx.x;
        if (i < nT) {
            int grow = (i < nnz) ? loadI(fidx, (size_t)i, i64)
                                 : N + loadI(eidx, (size_t)(i - nnz), i64);
            atomicAdd(&lh[grow >> RSH], 1);
        }
    }
    __syncthreads();
    if (threadIdx.x < KMAX) {
        int c = lh[threadIdx.x];
        cntPB[(size_t)threadIdx.x * nblk + blockIdx.x] = c;
        if (c) atomicAdd(&cntB[threadIdx.x], c);
    }
}

// single-block exclusive scan of bucket counts -> bqstart
__global__ void scanB_kernel(const int* cntB, int* bqstart, int K) {
    __shared__ int s[KMAX];
    int t = threadIdx.x;
    int x = (t < K) ? cntB[t] : 0;
    s[t] = x;
    __syncthreads();
    for (int off = 1; off < KMAX; off <<= 1) {
        int v = (t >= off) ? s[t - off] : 0;
        __syncthreads();
        s[t] += v;
        __syncthreads();
    }
    if (t < K) bqstart[t] = s[t] - x;
}

// one block per bucket: exclusive scan over the nblk per-block counts,
// rebased by bqstart -> cntPB becomes absolute write base per (bucket,block)
__global__ __launch_bounds__(1024)
void scanPB_kernel(int* cntPB, const int* bqstart, int nblk) {
    __shared__ int s[1024];
    const int b = blockIdx.x;
    const int t = threadIdx.x;
    int x = (t < nblk) ? cntPB[(size_t)b * nblk + t] : 0;
    s[t] = x;
    __syncthreads();
    for (int off = 1; off < 1024; off <<= 1) {
        int v = (t >= off) ? s[t - off] : 0;
        __syncthreads();
        s[t] += v;
        __syncthreads();
    }
    if (t < nblk) cntPB[(size_t)b * nblk + t] = bqstart[b] + s[t] - x;
}

// Pass A: register-held tile -> LDS bucket-sort -> coalesced flush to Q.
// stage 56KB + hist 2KB + lofs 2.05KB + delta 2KB = 63.5KB LDS, 2 blocks/CU.
__global__ __launch_bounds__(1024)
void bucketA_kernel(const void* fidx, const void* fval,
                    const void* eidx, const void* ew,
                    const int* flags, const int* cntPB, int2* Q,
                    int nnz, int nE, int N, int nblk) {
    __shared__ int2 stage[TILE_A];
    __shared__ int hist[KMAX];
    __shared__ int lofs[KMAX + 1];
    __shared__ int delta[KMAX];
    const int i64 = flags[1], bf16 = flags[0];
    const int nT = nnz + nE;
    const int base = blockIdx.x * TILE_A;
    const int t = threadIdx.x;
    if (t < KMAX) hist[t] = 0;
    __syncthreads();

    // phase 1: load tile into registers, LDS histogram with returned rank
    int key[EPT]; float val[EPT]; int bk[EPT]; int rk[EPT];
#pragma unroll
    for (int k = 0; k < EPT; k++) {
        int i = base + k * 1024 + t;
        bk[k] = -1; rk[k] = 0; key[k] = 0; val[k] = 0.f;
        if (i < nT) {
            int grow, c; float v;
            if (i < nnz) {
                grow = loadI(fidx, (size_t)i, i64);
                c    = loadI(fidx, (size_t)nnz + i, i64);
                v    = loadF(fval, (size_t)i, bf16);
            } else {
                int j = i - nnz;
                grow = N + loadI(eidx, (size_t)j, i64);
                c    = loadI(eidx, (size_t)nE + j, i64);
                v    = loadF(ew, (size_t)j, bf16);
            }
            int b = grow >> RSH;
            bk[k]  = b;
            key[k] = ((grow & ((1 << RSH) - 1)) << 17) | c;
            val[k] = v;
            rk[k]  = atomicAdd(&hist[b], 1);
        }
    }
    __syncthreads();

    // phase 2: inclusive scan of counts (scratch in delta), then
    // lofs = exclusive scan (+ sentinel), delta = gbase - lofs
    int cnt = (t < KMAX) ? hist[t] : 0;
    if (t < KMAX) delta[t] = cnt;
    __syncthreads();
    for (int off2 = 1; off2 < KMAX; off2 <<= 1) {
        int v2 = (t >= off2 && t < KMAX) ? delta[t - off2] : 0;
        __syncthreads();
        if (t < KMAX) delta[t] += v2;
        __syncthreads();
    }
    if (t < KMAX) {
        int incl = delta[t];
        int excl = incl - cnt;
        lofs[t] = excl;
        if (t == KMAX - 1) lofs[KMAX] = incl;
        delta[t] = cntPB[(size_t)t * nblk + blockIdx.x] - excl;
    }
    __syncthreads();

    // phase 3: stage into LDS in bucket-sorted order
#pragma unroll
    for (int k = 0; k < EPT; k++) {
        if (bk[k] >= 0)
            stage[lofs[bk[k]] + rk[k]] = make_int2(key[k], __float_as_int(val[k]));
    }
    __syncthreads();

    // phase 4: linear flush; dest(p) = delta[b(p)] + p, b via binary search
    const int total = min(TILE_A, nT - base);
    for (int p = t; p < total; p += 1024) {
        int b = 0;
#pragma unroll
        for (int step = KMAX / 2; step; step >>= 1)
            if (lofs[b + step] <= p) b += step;
        Q[delta[b] + p] = stage[p];
    }
}

// Pass B: one 1024-thread block per bucket; LDS row hist + scan -> rp segment,
// scatter to P with LDS rank cursors. Scan is 512-wide (rows/bucket), guarded.
__global__ __launch_bounds__(1024)
void bucketB_kernel(const int2* Q, const int* bqstart, int* rp,
                    int2* P, int nT, int K) {
    __shared__ int lh[1 << RSH];
    __shared__ int s[1 << RSH];
    __shared__ int lstart[1 << RSH];
    const int b = blockIdx.x;
    const int t = threadIdx.x;
    const int start = bqstart[b];
    const int end = (b == K - 1) ? nT : bqstart[b + 1];
    if (t < (1 << RSH)) lh[t] = 0;
    __syncthreads();
    for (int i = start + t; i < end; i += 1024)
        atomicAdd(&lh[((unsigned)Q[i].x) >> 17], 1);
    __syncthreads();
    int x = (t < (1 << RSH)) ? lh[t] : 0;
    if (t < (1 << RSH)) s[t] = x;
    __syncthreads();
    for (int off = 1; off < (1 << RSH); off <<= 1) {
        int v = (t >= off && t < (1 << RSH)) ? s[t - off] : 0;
        __syncthreads();
        if (t < (1 << RSH)) s[t] += v;
        __syncthreads();
    }
    if (t < (1 << RSH)) {
        int rowstart = start + s[t] - x;
        rp[(b << RSH) + t] = rowstart;
        lstart[t] = rowstart;
        lh[t] = 0;
    }
    __syncthreads();
    for (int i = start + t; i < end; i += 1024) {
        int2 el = Q[i];
        int lr = ((unsigned)el.x) >> 17;
        int rank = atomicAdd(&lh[lr], 1);
        P[lstart[lr] + rank] = make_int2(el.x & 0x1FFFF, el.y);
    }
}

// 4 rows/wave feat gather: h = b1 + sum v*W1[c], stored fp8 (row*16+gl dword).
__global__ void gather_feat_kernel(const int* rp, const int2* P,
                                   const uint2* w1q, const void* b1,
                                   unsigned* hF8, const int* flags, int N) {
    int bf16 = flags[0];
    int wave = (blockIdx.x * blockDim.x + threadIdx.x) >> 6;
    int lane = threadIdx.x & 63;
    int g = lane >> 4, gl = lane & 15;
    int row = 4 * wave + g;
    int s = 0, e = 0;
    if (row < N) { s = rp[row]; e = rp[row + 1]; }
    float a0 = loadF(b1, (size_t)4 * gl,     bf16);
    float a1 = loadF(b1, (size_t)4 * gl + 1, bf16);
    float a2 = loadF(b1, (size_t)4 * gl + 2, bf16);
    float a3 = loadF(b1, (size_t)4 * gl + 3, bf16);
    const int sb = g << 4;
    for (int base = s; base < e; base += 16) {
        int idx = base + gl;
        int cl = 0; float vl = 0.f;
        if (idx < e) ntload(P, idx, &cl, &vl);
        int cnt = min(16, e - base);
        int j = 0;
        for (; j + 4 <= cnt; j += 4) {
            int   c0 = __shfl(cl, sb + j),     c1 = __shfl(cl, sb + j + 1);
            int   c2 = __shfl(cl, sb + j + 2), c3 = __shfl(cl, sb + j + 3);
            float v0 = __shfl(vl, sb + j),     v1 = __shfl(vl, sb + j + 1);
            float v2 = __shfl(vl, sb + j + 2), v3 = __shfl(vl, sb + j + 3);
            uint2 u0 = w1q[c0 * 16 + gl];
            uint2 u1 = w1q[c1 * 16 + gl];
            uint2 u2 = w1q[c2 * 16 + gl];
            uint2 u3 = w1q[c3 * 16 + gl];
            a0 += v0 * bflo(u0.x); a1 += v0 * bfhi(u0.x);
            a2 += v0 * bflo(u0.y); a3 += v0 * bfhi(u0.y);
            a0 += v1 * bflo(u1.x); a1 += v1 * bfhi(u1.x);
            a2 += v1 * bflo(u1.y); a3 += v1 * bfhi(u1.y);
            a0 += v2 * bflo(u2.x); a1 += v2 * bfhi(u2.x);
            a2 += v2 * bflo(u2.y); a3 += v2 * bfhi(u2.y);
            a0 += v3 * bflo(u3.x); a1 += v3 * bfhi(u3.x);
            a2 += v3 * bflo(u3.y); a3 += v3 * bfhi(u3.y);
        }
        for (; j < cnt; j++) {
            int   c = __shfl(cl, sb + j);
            float v = __shfl(vl, sb + j);
            uint2 u = w1q[c * 16 + gl];
            a0 += v * bflo(u.x); a1 += v * bfhi(u.x);
            a2 += v * bflo(u.y); a3 += v * bfhi(u.y);
        }
    }
    if (row < N) hF8[row * 16 + gl] = fp8pack4(a0, a1, a2, a3);
}

// Merged propagation, NO epilogue: h2 = relu(A @ h), fp8 in / fp8 out.
__global__ void gather_edge_h2_kernel(const int* rp, const int2* P,
                                      const unsigned* hF8, unsigned* h2F8,
                                      int N) {
    int wave = (blockIdx.x * blockDim.x + threadIdx.x) >> 6;
    int lane = threadIdx.x & 63;
    int g = lane >> 4, gl = lane & 15;
    int row = 4 * wave + g;
    int s = 0, e = 0;
    if (row < N) { s = rp[N + row]; e = rp[N + row + 1]; }
    float a0 = 0.f, a1 = 0.f, a2 = 0.f, a3 = 0.f;
    const int sb = g << 4;
    for (int base = s; base < e; base += 16) {
        int idx = base + gl;
        int cl = 0; float wl = 0.f;
        if (idx < e) ntload(P, idx, &cl, &wl);
        int cnt = min(16, e - base);
        int j = 0;
        for (; j + 8 <= cnt; j += 8) {
            int   c0 = __shfl(cl, sb + j),     c1 = __shfl(cl, sb + j + 1);
            int   c2 = __shfl(cl, sb + j + 2), c3 = __shfl(cl, sb + j + 3);
            int   c4 = __shfl(cl, sb + j + 4), c5 = __shfl(cl, sb + j + 5);
            int   c6 = __shfl(cl, sb + j + 6), c7 = __shfl(cl, sb + j + 7);
            float w0 = __shfl(wl, sb + j),     w1 = __shfl(wl, sb + j + 1);
            float w2 = __shfl(wl, sb + j + 2), w3 = __shfl(wl, sb + j + 3);
            float w4 = __shfl(wl, sb + j + 4), w5 = __shfl(wl, sb + j + 5);
            float w6 = __shfl(wl, sb + j + 6), w7 = __shfl(wl, sb + j + 7);
            int u0 = (int)hF8[c0 * 16 + gl];
            int u1 = (int)hF8[c1 * 16 + gl];
            int u2 = (int)hF8[c2 * 16 + gl];
            int u3 = (int)hF8[c3 * 16 + gl];
            int u4 = (int)hF8[c4 * 16 + gl];
            int u5 = (int)hF8[c5 * 16 + gl];
            int u6 = (int)hF8[c6 * 16 + gl];
            int u7 = (int)hF8[c7 * 16 + gl];
            a0 += w0 * __builtin_amdgcn_cvt_f32_fp8(u0, 0);
            a1 += w0 * __builtin_amdgcn_cvt_f32_fp8(u0, 1);
            a2 += w0 * __builtin_amdgcn_cvt_f32_fp8(u0, 2);
            a3 += w0 * __builtin_amdgcn_cvt_f32_fp8(u0, 3);
            a0 += w1 * __builtin_amdgcn_cvt_f32_fp8(u1, 0);
            a1 += w1 * __builtin_amdgcn_cvt_f32_fp8(u1, 1);
            a2 += w1 * __builtin_amdgcn_cvt_f32_fp8(u1, 2);
            a3 += w1 * __builtin_amdgcn_cvt_f32_fp8(u1, 3);
            a0 += w2 * __builtin_amdgcn_cvt_f32_fp8(u2, 0);
            a1 += w2 * __builtin_amdgcn_cvt_f32_fp8(u2, 1);
            a2 += w2 * __builtin_amdgcn_cvt_f32_fp8(u2, 2);
            a3 += w2 * __builtin_amdgcn_cvt_f32_fp8(u2, 3);
            a0 += w3 * __builtin_amdgcn_cvt_f32_fp8(u3, 0);
            a1 += w3 * __builtin_amdgcn_cvt_f32_fp8(u3, 1);
            a2 += w3 * __builtin_amdgcn_cvt_f32_fp8(u3, 2);
            a3 += w3 * __builtin_amdgcn_cvt_f32_fp8(u3, 3);
            a0 += w4 * __builtin_amdgcn_cvt_f32_fp8(u4, 0);
            a1 += w4 * __builtin_amdgcn_cvt_f32_fp8(u4, 1);
            a2 += w4 * __builtin_amdgcn_cvt_f32_fp8(u4, 2);
            a3 += w4 * __builtin_amdgcn_cvt_f32_fp8(u4, 3);
            a0 += w5 * __builtin_amdgcn_cvt_f32_fp8(u5, 0);
            a1 += w5 * __builtin_amdgcn_cvt_f32_fp8(u5, 1);
            a2 += w5 * __builtin_amdgcn_cvt_f32_fp8(u5, 2);
            a3 += w5 * __builtin_amdgcn_cvt_f32_fp8(u5, 3);
            a0 += w6 * __builtin_amdgcn_cvt_f32_fp8(u6, 0);
            a1 += w6 * __builtin_amdgcn_cvt_f32_fp8(u6, 1);
            a2 += w6 * __builtin_amdgcn_cvt_f32_fp8(u6, 2);
            a3 += w6 * __builtin_amdgcn_cvt_f32_fp8(u6, 3);
            a0 += w7 * __builtin_amdgcn_cvt_f32_fp8(u7, 0);
            a1 += w7 * __builtin_amdgcn_cvt_f32_fp8(u7, 1);
            a2 += w7 * __builtin_amdgcn_cvt_f32_fp8(u7, 2);
            a3 += w7 * __builtin_amdgcn_cvt_f32_fp8(u7, 3);
        }
        for (; j < cnt; j++) {
            int   c = __shfl(cl, sb + j);
            float w = __shfl(wl, sb + j);
            int u = (int)hF8[c * 16 + gl];
            a0 += w * __builtin_amdgcn_cvt_f32_fp8(u, 0);
            a1 += w * __builtin_amdgcn_cvt_f32_fp8(u, 1);
            a2 += w * __builtin_amdgcn_cvt_f32_fp8(u, 2);
            a3 += w * __builtin_amdgcn_cvt_f32_fp8(u, 3);
        }
    }
    if (row < N)
        h2F8[row * 16 + gl] = fp8pack4(fmaxf(a0, 0.f), fmaxf(a1, 0.f),
                                       fmaxf(a2, 0.f), fmaxf(a3, 0.f));
}

// Dense: z = relu_h2 @ W2 + b2, fp8 out. 16 rows/wave, 4 independent
// accumulator chains (breaks the serial FMA dependency), uint4 row loads.
__global__ void dense_kernel(const unsigned* h2F8, const void* W2, const void* b2,
                             unsigned char* zb, const int* flags, int N) {
    int bf16 = flags[0];
    int wave = (int)((blockIdx.x * blockDim.x + threadIdx.x) >> 6);
    int lane = threadIdx.x & 63;
    int jj = (lane < LAB) ? lane : 0;
    float w2c[HID];
#pragma unroll
    for (int k = 0; k < HID; k++) w2c[k] = loadF(W2, (size_t)k * LAB + jj, bf16);
    float bias = loadF(b2, (size_t)jj, bf16);
    int r0 = wave * 16;
    int r1 = min(r0 + 16, N);
    for (int r = r0; r < r1; r++) {
        const uint4* hr4 = (const uint4*)(h2F8 + (size_t)r * 16);
        uint4 q0 = hr4[0], q1 = hr4[1], q2 = hr4[2], q3 = hr4[3];
        float acc0 = bias, acc1 = 0.f, acc2 = 0.f, acc3 = 0.f;
#define DK(ACC, D, KB)                                              \
        ACC += __builtin_amdgcn_cvt_f32_fp8((int)(D), 0) * w2c[KB]; \
        ACC += __builtin_amdgcn_cvt_f32_fp8((int)(D), 1) * w2c[(KB) + 1]; \
        ACC += __builtin_amdgcn_cvt_f32_fp8((int)(D), 2) * w2c[(KB) + 2]; \
        ACC += __builtin_amdgcn_cvt_f32_fp8((int)(D), 3) * w2c[(KB) + 3];
        DK(acc0, q0.x,  0) DK(acc1, q0.y,  4) DK(acc2, q0.z,  8) DK(acc3, q0.w, 12)
        DK(acc0, q1.x, 16) DK(acc1, q1.y, 20) DK(acc2, q1.z, 24) DK(acc3, q1.w, 28)
        DK(acc0, q2.x, 32) DK(acc1, q2.y, 36) DK(acc2, q2.z, 40) DK(acc3, q2.w, 44)
        DK(acc0, q3.x, 48) DK(acc1, q3.y, 52) DK(acc2, q3.z, 56) DK(acc3, q3.w, 60)
#undef DK
        float acc = (acc0 + acc1) + (acc2 + acc3);
        if (lane < LAB) {
            int pk = __builtin_amdgcn_cvt_pk_fp8_f32(acc, acc, 0, false);
            zb[(size_t)r * LAB + lane] = (unsigned char)(pk & 0xFF);
        }
    }
}

// 4 rows/wave: z2 = A@z (fp8 gather), fused log_softmax -> out.
__global__ void gather_edge_lsm_kernel(const int* rp, const int2* P,
                                       const unsigned* zF8, void* out,
                                       const int* flags, int N) {
    int bf16 = flags[0];
    int wave = (blockIdx.x * blockDim.x + threadIdx.x) >> 6;
    int lane = threadIdx.x & 63;
    int g = lane >> 4, gl = lane & 15;
    int row = 4 * wave + g;
    int s = 0, e = 0;
    if (row < N) { s = rp[N + row]; e = rp[N + row + 1]; }
    float a0 = 0.f, a1 = 0.f, a2 = 0.f, a3 = 0.f;
    const int sb = g << 4;
    const int act = (gl < 10);
    for (int base = s; base < e; base += 16) {
        int idx = base + gl;
        int cl = 0; float wl = 0.f;
        if (idx < e) ntload(P, idx, &cl, &wl);
        int cnt = min(16, e - base);
        int j = 0;
        for (; j + 4 <= cnt; j += 4) {
            int   c0 = __shfl(cl, sb + j),     c1 = __shfl(cl, sb + j + 1);
            int   c2 = __shfl(cl, sb + j + 2), c3 = __shfl(cl, sb + j + 3);
            float w0 = __shfl(wl, sb + j),     w1 = __shfl(wl, sb + j + 1);
            float w2 = __shfl(wl, sb + j + 2), w3 = __shfl(wl, sb + j + 3);
            if (act) {
                int u0 = (int)zF8[c0 * 10 + gl];
                int u1 = (int)zF8[c1 * 10 + gl];
                int u2 = (int)zF8[c2 * 10 + gl];
                int u3 = (int)zF8[c3 * 10 + gl];
                a0 += w0 * __builtin_amdgcn_cvt_f32_fp8(u0, 0);
                a1 += w0 * __builtin_amdgcn_cvt_f32_fp8(u0, 1);
                a2 += w0 * __builtin_amdgcn_cvt_f32_fp8(u0, 2);
                a3 += w0 * __builtin_amdgcn_cvt_f32_fp8(u0, 3);
                a0 += w1 * __builtin_amdgcn_cvt_f32_fp8(u1, 0);
                a1 += w1 * __builtin_amdgcn_cvt_f32_fp8(u1, 1);
                a2 += w1 * __builtin_amdgcn_cvt_f32_fp8(u1, 2);
                a3 += w1 * __builtin_amdgcn_cvt_f32_fp8(u1, 3);
                a0 += w2 * __builtin_amdgcn_cvt_f32_fp8(u2, 0);
                a1 += w2 * __builtin_amdgcn_cvt_f32_fp8(u2, 1);
                a2 += w2 * __builtin_amdgcn_cvt_f32_fp8(u2, 2);
                a3 += w2 * __builtin_amdgcn_cvt_f32_fp8(u2, 3);
                a0 += w3 * __builtin_amdgcn_cvt_f32_fp8(u3, 0);
                a1 += w3 * __builtin_amdgcn_cvt_f32_fp8(u3, 1);
                a2 += w3 * __builtin_amdgcn_cvt_f32_fp8(u3, 2);
                a3 += w3 * __builtin_amdgcn_cvt_f32_fp8(u3, 3);
            }
        }
        for (; j < cnt; j++) {
            int   c = __shfl(cl, sb + j);
            float w = __shfl(wl, sb + j);
            if (act) {
                int u = (int)zF8[c * 10 + gl];
                a0 += w * __builtin_amdgcn_cvt_f32_fp8(u, 0);
                a1 += w * __builtin_amdgcn_cvt_f32_fp8(u, 1);
                a2 += w * __builtin_amdgcn_cvt_f32_fp8(u, 2);
                a3 += w * __builtin_amdgcn_cvt_f32_fp8(u, 3);
            }
        }
    }
    float m = act ? fmaxf(fmaxf(a0, a1), fmaxf(a2, a3)) : -INFINITY;
#pragma unroll
    for (int off = 8; off; off >>= 1) m = fmaxf(m, __shfl_xor(m, off));
    float es = act ? (__expf(a0 - m) + __expf(a1 - m) + __expf(a2 - m) + __expf(a3 - m)) : 0.f;
#pragma unroll
    for (int off = 8; off; off >>= 1) es += __shfl_xor(es, off);
    float lse = m + __logf(es);
    if (act && row < N) {
        float o0 = a0 - lse, o1 = a1 - lse, o2 = a2 - lse, o3 = a3 - lse;
        if (bf16) {
            ((uint2*)out)[(size_t)row * 10 + gl] =
                make_uint2(bfpack(o0, o1), bfpack(o2, o3));
        } else {
            float4 v = make_float4(o0, o1, o2, o3);
            ((float4*)out)[(size_t)row * 10 + gl] = v;
        }
    }
}

extern "C" void kernel_launch(void* const* d_in, const int* in_sizes, int n_in,
                              void* d_out, int out_size, void* d_ws, size_t ws_size,
                              hipStream_t stream) {
    const void* fidx = d_in[0];
    const void* fval = d_in[1];
    const void* eidx = d_in[2];
    const void* ew   = d_in[3];
    const void* W1   = d_in[4];
    const void* b1   = d_in[5];
    const void* W2   = d_in[6];
    const void* b2   = d_in[7];

    const int nnz = in_sizes[1];          // 2,500,000
    const int nW1 = in_sizes[4];          // 2048*64
    const int nE  = in_sizes[3];          // 1,700,000
    const int N   = out_size / LAB;       // 100,000
    const int M   = 2 * N;
    const int nT  = nnz + nE;
    const int K   = (M + (1 << RSH) - 1) >> RSH;   // 391 buckets
    const int NBLK = (nT + TILE_A - 1) / TILE_A;   // 586 tile blocks

    auto align256 = [](size_t x) { return (x + 255) & ~(size_t)255; };
    char* ws = (char*)d_ws;
    size_t off = 0;
    int*   flags   = (int*)(ws + off);   off += 256;
    // front: hF8 (6.4MB) | h2F8 (6.4MB) | zF8 (4MB); Q (int2, 33.6MB) overlays
    // front and dies before gather_feat writes hF8.
    char*  front   = ws + off;
    unsigned* hF8  = (unsigned*)front;                       // N*16 dwords
    unsigned* h2F8 = hF8 + (size_t)N * 16;                   // N*16 dwords
    unsigned char* zb = (unsigned char*)(h2F8 + (size_t)N * 16);  // N*40 B
    size_t frontBytes = (size_t)N * (64 + 64 + 40);
    size_t qBytes     = (size_t)nT * 8;
    off += align256(frontBytes > qBytes ? frontBytes : qBytes);
    int2*  P       = (int2*)(ws + off);  off += align256((size_t)nT * 8);
    int*   rp      = (int*)(ws + off);   off += align256(((size_t)KMAX << RSH) * 4 + 16);
    uint2* w1q     = (uint2*)(ws + off); off += align256((size_t)nW1 * 2);
    int*   cntB    = (int*)(ws + off);   off += KMAX * 4;
    int*   bqstart = (int*)(ws + off);   off += KMAX * 4;
    int*   cntPB   = (int*)(ws + off);   off += align256((size_t)KMAX * NBLK * 4);
    int2*  Q       = (int2*)front;

    // 1. dtype probe
    probe_kernel<<<1, 64, 0, stream>>>(b1, fidx, flags);

    // 2. zero bucket histogram; stage W1 packed
    zero_kernel<<<1, 256, 0, stream>>>((int4*)cntB, KMAX / 4);
    convw1_kernel<<<(nW1 / 4 + 255) / 256, 256, 0, stream>>>(W1, w1q, flags, nW1 / 4);

    // 3. bucket histogram, tiled like bucketA -> per-(bucket,block) counts
    histB_kernel<<<NBLK, 1024, 0, stream>>>(fidx, eidx, cntB, cntPB,
                                            flags, nnz, nE, N, NBLK);

    // 4. bucket scan -> bucket starts
    scanB_kernel<<<1, KMAX, 0, stream>>>(cntB, bqstart, K);

    // 5. per-bucket scan over blocks -> absolute write base per (bucket,block)
    scanPB_kernel<<<K, 1024, 0, stream>>>(cntPB, bqstart, NBLK);

    // 6. pass A: register tile -> LDS bucket-sort -> coalesced scatter into Q
    bucketA_kernel<<<NBLK, 1024, 0, stream>>>(fidx, fval, eidx, ew, flags,
                                              cntPB, Q, nnz, nE, N, NBLK);

    // 7. pass B: per-bucket row hist/scan in LDS, rp segment, scatter -> P
    bucketB_kernel<<<K, 1024, 0, stream>>>(Q, bqstart, rp, P, nT, K);

    // 8. h = sparse_features @ W1 + b1 -> fp8
    int nwaves = (N + 3) / 4;
    int gblocks = (int)(((size_t)nwaves * 64 + 255) / 256);
    gather_feat_kernel<<<gblocks, 256, 0, stream>>>(rp, P, w1q, b1, hF8, flags, N);

    // 9. h2 = relu(A @ h) -> fp8 (gather-only, no epilogue)
    gather_edge_h2_kernel<<<gblocks, 256, 0, stream>>>(rp, P, hF8, h2F8, N);

    // 10. z = h2 @ W2 + b2 -> fp8 (16 rows/wave, 4 acc chains)
    int dwaves = (N + 15) / 16;
    int dblocks = (dwaves * 64 + 255) / 256;
    dense_kernel<<<dblocks, 256, 0, stream>>>(h2F8, W2, b2, zb, flags, N);

    // 11. out = log_softmax(A @ z)
    gather_edge_lsm_kernel<<<gblocks, 256, 0, stream>>>(rp, P, (const unsigned*)zb,
                                                        d_out, flags, N);
}

// Round 6
// 378.522 us; speedup vs baseline: 1.0308x; 1.0308x over previous
//
#include <hip/hip_runtime.h>
#include <hip/hip_bf16.h>

// ---------------------------------------------------------------------------
// GCN forward on MI355X — round 19.
// R18 post-mortem: dense 50->101us. VALU dropped 42->17%, WRITE 3.9->41.8MB,
// FETCH 3.2->12.4MB -> the uint4 up-front loads + 2x grid broke R17's clean
// load/FMA interleave and store line-merging; 3 variables changed at once.
// R19: ONE variable. dense = R17 memory shape exactly (32 rows/wave, 16
// scalar dword loads, same grid) + round-robin the dwords over 4 independent
// acc chains (pure register reassociation). If R17's serial-chain theory is
// right: dense ~50 -> ~18-28us, VALU -> 65-85%, WRITE back to ~3.9MB.
// Everything else unchanged from R17/R18 (bucketA parked at 50us).
// ---------------------------------------------------------------------------

#define HID 64
#define LAB 40
#define RSH 9          // 512 rows per bucket
#define KMAX 512       // max buckets (runtime K = 391)
#define TILE_A 7168    // elements per tile block (1024 threads x 7)
#define EPT 7          // elements per thread in bucketA/histB

__device__ __forceinline__ float loadF(const void* p, size_t i, int bf16) {
    if (bf16) return __bfloat162float(((const __hip_bfloat16*)p)[i]);
    return ((const float*)p)[i];
}

__device__ __forceinline__ int loadI(const void* p, size_t i, int i64) {
    if (i64) return (int)(((const long long*)p)[i]);
    return ((const int*)p)[i];
}

// packed bf16x2 helpers
__device__ __forceinline__ float bflo(unsigned v) { return __uint_as_float(v << 16); }
__device__ __forceinline__ float bfhi(unsigned v) { return __uint_as_float(v & 0xFFFF0000u); }
__device__ __forceinline__ unsigned bfr16(float x) {
    unsigned u = __float_as_uint(x);
    return (u + 0x7FFFu + ((u >> 16) & 1u)) >> 16;
}
__device__ __forceinline__ unsigned bfpack(float lo, float hi) {
    return bfr16(lo) | (bfr16(hi) << 16);
}

// fp8 e4m3 HW converts
__device__ __forceinline__ unsigned fp8pack4(float a, float b, float c, float d) {
    int r = __builtin_amdgcn_cvt_pk_fp8_f32(a, b, 0, false);
    r = __builtin_amdgcn_cvt_pk_fp8_f32(c, d, r, true);
    return (unsigned)r;
}

// nontemporal int2 load (keep P streams out of L2)
__device__ __forceinline__ void ntload(const int2* P, int idx, int* c, float* w) {
    long long raw = __builtin_nontemporal_load((const long long*)P + idx);
    *c = (int)(unsigned)(raw & 0xFFFFFFFFll);
    *w = __int_as_float((int)(raw >> 32));
}

// dtype probe (validated R1-R18)
__global__ void probe_kernel(const void* b1p, const void* fidxp, int* flags) {
    if (threadIdx.x == 0 && blockIdx.x == 0) {
        const unsigned short* u = (const unsigned short*)b1p;
        int bf16 = 1;
        for (int i = 0; i < 64; i += 2)
            if ((unsigned short)(u[i] & 0x7FFF) >= 0x3E80) { bf16 = 0; break; }
        const int* ip = (const int*)fidxp;
        int i64 = 1;
        for (int i = 1; i < 128; i += 2)
            if (ip[i] != 0) { i64 = 0; break; }
        flags[0] = bf16; flags[1] = i64; flags[2] = 0; flags[3] = 0;
    }
}

__global__ void zero_kernel(int4* p, int n4) {
    int i = blockIdx.x * blockDim.x + threadIdx.x;
    if (i < n4) p[i] = make_int4(0, 0, 0, 0);
}

// W1 -> packed bf16 staging: entry i = features 4i..4i+3 (uint2)
__global__ void convw1_kernel(const void* W1, uint2* w1q, const int* flags, int ne) {
    int i = blockIdx.x * blockDim.x + threadIdx.x;
    if (i < ne) {
        float f0 = loadF(W1, (size_t)4 * i,     flags[0]);
        float f1 = loadF(W1, (size_t)4 * i + 1, flags[0]);
        float f2 = loadF(W1, (size_t)4 * i + 2, flags[0]);
        float f3 = loadF(W1, (size_t)4 * i + 3, flags[0]);
        w1q[i] = make_uint2(bfpack(f0, f1), bfpack(f2, f3));
    }
}

// Bucket histogram, tiled EXACTLY like bucketA (one block per TILE_A run).
// Emits per-(bucket,block) counts cntPB[b*nblk+blk] + global totals cntB.
__global__ __launch_bounds__(1024)
void histB_kernel(const void* fidx, const void* eidx, int* cntB, int* cntPB,
                  const int* flags, int nnz, int nE, int N, int nblk) {
    __shared__ int lh[KMAX];
    if (threadIdx.x < KMAX) lh[threadIdx.x] = 0;
    __syncthreads();
    const int i64 = flags[1];
    const int nT = nnz + nE;
    const int base = blockIdx.x * TILE_A;
#pragma unroll
    for (int k = 0; k < EPT; k++) {
        int i = base + k * 1024 + threadIdx.x;
        if (i < nT) {
            int grow = (i < nnz) ? loadI(fidx, (size_t)i, i64)
                                 : N + loadI(eidx, (size_t)(i - nnz), i64);
            atomicAdd(&lh[grow >> RSH], 1);
        }
    }
    __syncthreads();
    if (threadIdx.x < KMAX) {
        int c = lh[threadIdx.x];
        cntPB[(size_t)threadIdx.x * nblk + blockIdx.x] = c;
        if (c) atomicAdd(&cntB[threadIdx.x], c);
    }
}

// single-block exclusive scan of bucket counts -> bqstart
__global__ void scanB_kernel(const int* cntB, int* bqstart, int K) {
    __shared__ int s[KMAX];
    int t = threadIdx.x;
    int x = (t < K) ? cntB[t] : 0;
    s[t] = x;
    __syncthreads();
    for (int off = 1; off < KMAX; off <<= 1) {
        int v = (t >= off) ? s[t - off] : 0;
        __syncthreads();
        s[t] += v;
        __syncthreads();
    }
    if (t < K) bqstart[t] = s[t] - x;
}

// one block per bucket: exclusive scan over the nblk per-block counts,
// rebased by bqstart -> cntPB becomes absolute write base per (bucket,block)
__global__ __launch_bounds__(1024)
void scanPB_kernel(int* cntPB, const int* bqstart, int nblk) {
    __shared__ int s[1024];
    const int b = blockIdx.x;
    const int t = threadIdx.x;
    int x = (t < nblk) ? cntPB[(size_t)b * nblk + t] : 0;
    s[t] = x;
    __syncthreads();
    for (int off = 1; off < 1024; off <<= 1) {
        int v = (t >= off) ? s[t - off] : 0;
        __syncthreads();
        s[t] += v;
        __syncthreads();
    }
    if (t < nblk) cntPB[(size_t)b * nblk + t] = bqstart[b] + s[t] - x;
}

// Pass A: register-held tile -> LDS bucket-sort -> coalesced flush to Q.
// stage 56KB + hist 2KB + lofs 2.05KB + delta 2KB = 63.5KB LDS, 2 blocks/CU.
__global__ __launch_bounds__(1024)
void bucketA_kernel(const void* fidx, const void* fval,
                    const void* eidx, const void* ew,
                    const int* flags, const int* cntPB, int2* Q,
                    int nnz, int nE, int N, int nblk) {
    __shared__ int2 stage[TILE_A];
    __shared__ int hist[KMAX];
    __shared__ int lofs[KMAX + 1];
    __shared__ int delta[KMAX];
    const int i64 = flags[1], bf16 = flags[0];
    const int nT = nnz + nE;
    const int base = blockIdx.x * TILE_A;
    const int t = threadIdx.x;
    if (t < KMAX) hist[t] = 0;
    __syncthreads();

    // phase 1: load tile into registers, LDS histogram with returned rank
    int key[EPT]; float val[EPT]; int bk[EPT]; int rk[EPT];
#pragma unroll
    for (int k = 0; k < EPT; k++) {
        int i = base + k * 1024 + t;
        bk[k] = -1; rk[k] = 0; key[k] = 0; val[k] = 0.f;
        if (i < nT) {
            int grow, c; float v;
            if (i < nnz) {
                grow = loadI(fidx, (size_t)i, i64);
                c    = loadI(fidx, (size_t)nnz + i, i64);
                v    = loadF(fval, (size_t)i, bf16);
            } else {
                int j = i - nnz;
                grow = N + loadI(eidx, (size_t)j, i64);
                c    = loadI(eidx, (size_t)nE + j, i64);
                v    = loadF(ew, (size_t)j, bf16);
            }
            int b = grow >> RSH;
            bk[k]  = b;
            key[k] = ((grow & ((1 << RSH) - 1)) << 17) | c;
            val[k] = v;
            rk[k]  = atomicAdd(&hist[b], 1);
        }
    }
    __syncthreads();

    // phase 2: inclusive scan of counts (scratch in delta), then
    // lofs = exclusive scan (+ sentinel), delta = gbase - lofs
    int cnt = (t < KMAX) ? hist[t] : 0;
    if (t < KMAX) delta[t] = cnt;
    __syncthreads();
    for (int off2 = 1; off2 < KMAX; off2 <<= 1) {
        int v2 = (t >= off2 && t < KMAX) ? delta[t - off2] : 0;
        __syncthreads();
        if (t < KMAX) delta[t] += v2;
        __syncthreads();
    }
    if (t < KMAX) {
        int incl = delta[t];
        int excl = incl - cnt;
        lofs[t] = excl;
        if (t == KMAX - 1) lofs[KMAX] = incl;
        delta[t] = cntPB[(size_t)t * nblk + blockIdx.x] - excl;
    }
    __syncthreads();

    // phase 3: stage into LDS in bucket-sorted order
#pragma unroll
    for (int k = 0; k < EPT; k++) {
        if (bk[k] >= 0)
            stage[lofs[bk[k]] + rk[k]] = make_int2(key[k], __float_as_int(val[k]));
    }
    __syncthreads();

    // phase 4: linear flush; dest(p) = delta[b(p)] + p, b via binary search
    const int total = min(TILE_A, nT - base);
    for (int p = t; p < total; p += 1024) {
        int b = 0;
#pragma unroll
        for (int step = KMAX / 2; step; step >>= 1)
            if (lofs[b + step] <= p) b += step;
        Q[delta[b] + p] = stage[p];
    }
}

// Pass B: one 1024-thread block per bucket; LDS row hist + scan -> rp segment,
// scatter to P with LDS rank cursors. Scan is 512-wide (rows/bucket), guarded.
__global__ __launch_bounds__(1024)
void bucketB_kernel(const int2* Q, const int* bqstart, int* rp,
                    int2* P, int nT, int K) {
    __shared__ int lh[1 << RSH];
    __shared__ int s[1 << RSH];
    __shared__ int lstart[1 << RSH];
    const int b = blockIdx.x;
    const int t = threadIdx.x;
    const int start = bqstart[b];
    const int end = (b == K - 1) ? nT : bqstart[b + 1];
    if (t < (1 << RSH)) lh[t] = 0;
    __syncthreads();
    for (int i = start + t; i < end; i += 1024)
        atomicAdd(&lh[((unsigned)Q[i].x) >> 17], 1);
    __syncthreads();
    int x = (t < (1 << RSH)) ? lh[t] : 0;
    if (t < (1 << RSH)) s[t] = x;
    __syncthreads();
    for (int off = 1; off < (1 << RSH); off <<= 1) {
        int v = (t >= off && t < (1 << RSH)) ? s[t - off] : 0;
        __syncthreads();
        if (t < (1 << RSH)) s[t] += v;
        __syncthreads();
    }
    if (t < (1 << RSH)) {
        int rowstart = start + s[t] - x;
        rp[(b << RSH) + t] = rowstart;
        lstart[t] = rowstart;
        lh[t] = 0;
    }
    __syncthreads();
    for (int i = start + t; i < end; i += 1024) {
        int2 el = Q[i];
        int lr = ((unsigned)el.x) >> 17;
        int rank = atomicAdd(&lh[lr], 1);
        P[lstart[lr] + rank] = make_int2(el.x & 0x1FFFF, el.y);
    }
}

// 4 rows/wave feat gather: h = b1 + sum v*W1[c], stored fp8 (row*16+gl dword).
__global__ void gather_feat_kernel(const int* rp, const int2* P,
                                   const uint2* w1q, const void* b1,
                                   unsigned* hF8, const int* flags, int N) {
    int bf16 = flags[0];
    int wave = (blockIdx.x * blockDim.x + threadIdx.x) >> 6;
    int lane = threadIdx.x & 63;
    int g = lane >> 4, gl = lane & 15;
    int row = 4 * wave + g;
    int s = 0, e = 0;
    if (row < N) { s = rp[row]; e = rp[row + 1]; }
    float a0 = loadF(b1, (size_t)4 * gl,     bf16);
    float a1 = loadF(b1, (size_t)4 * gl + 1, bf16);
    float a2 = loadF(b1, (size_t)4 * gl + 2, bf16);
    float a3 = loadF(b1, (size_t)4 * gl + 3, bf16);
    const int sb = g << 4;
    for (int base = s; base < e; base += 16) {
        int idx = base + gl;
        int cl = 0; float vl = 0.f;
        if (idx < e) ntload(P, idx, &cl, &vl);
        int cnt = min(16, e - base);
        int j = 0;
        for (; j + 4 <= cnt; j += 4) {
            int   c0 = __shfl(cl, sb + j),     c1 = __shfl(cl, sb + j + 1);
            int   c2 = __shfl(cl, sb + j + 2), c3 = __shfl(cl, sb + j + 3);
            float v0 = __shfl(vl, sb + j),     v1 = __shfl(vl, sb + j + 1);
            float v2 = __shfl(vl, sb + j + 2), v3 = __shfl(vl, sb + j + 3);
            uint2 u0 = w1q[c0 * 16 + gl];
            uint2 u1 = w1q[c1 * 16 + gl];
            uint2 u2 = w1q[c2 * 16 + gl];
            uint2 u3 = w1q[c3 * 16 + gl];
            a0 += v0 * bflo(u0.x); a1 += v0 * bfhi(u0.x);
            a2 += v0 * bflo(u0.y); a3 += v0 * bfhi(u0.y);
            a0 += v1 * bflo(u1.x); a1 += v1 * bfhi(u1.x);
            a2 += v1 * bflo(u1.y); a3 += v1 * bfhi(u1.y);
            a0 += v2 * bflo(u2.x); a1 += v2 * bfhi(u2.x);
            a2 += v2 * bflo(u2.y); a3 += v2 * bfhi(u2.y);
            a0 += v3 * bflo(u3.x); a1 += v3 * bfhi(u3.x);
            a2 += v3 * bflo(u3.y); a3 += v3 * bfhi(u3.y);
        }
        for (; j < cnt; j++) {
            int   c = __shfl(cl, sb + j);
            float v = __shfl(vl, sb + j);
            uint2 u = w1q[c * 16 + gl];
            a0 += v * bflo(u.x); a1 += v * bfhi(u.x);
            a2 += v * bflo(u.y); a3 += v * bfhi(u.y);
        }
    }
    if (row < N) hF8[row * 16 + gl] = fp8pack4(a0, a1, a2, a3);
}

// Merged propagation, NO epilogue: h2 = relu(A @ h), fp8 in / fp8 out.
__global__ void gather_edge_h2_kernel(const int* rp, const int2* P,
                                      const unsigned* hF8, unsigned* h2F8,
                                      int N) {
    int wave = (blockIdx.x * blockDim.x + threadIdx.x) >> 6;
    int lane = threadIdx.x & 63;
    int g = lane >> 4, gl = lane & 15;
    int row = 4 * wave + g;
    int s = 0, e = 0;
    if (row < N) { s = rp[N + row]; e = rp[N + row + 1]; }
    float a0 = 0.f, a1 = 0.f, a2 = 0.f, a3 = 0.f;
    const int sb = g << 4;
    for (int base = s; base < e; base += 16) {
        int idx = base + gl;
        int cl = 0; float wl = 0.f;
        if (idx < e) ntload(P, idx, &cl, &wl);
        int cnt = min(16, e - base);
        int j = 0;
        for (; j + 8 <= cnt; j += 8) {
            int   c0 = __shfl(cl, sb + j),     c1 = __shfl(cl, sb + j + 1);
            int   c2 = __shfl(cl, sb + j + 2), c3 = __shfl(cl, sb + j + 3);
            int   c4 = __shfl(cl, sb + j + 4), c5 = __shfl(cl, sb + j + 5);
            int   c6 = __shfl(cl, sb + j + 6), c7 = __shfl(cl, sb + j + 7);
            float w0 = __shfl(wl, sb + j),     w1 = __shfl(wl, sb + j + 1);
            float w2 = __shfl(wl, sb + j + 2), w3 = __shfl(wl, sb + j + 3);
            float w4 = __shfl(wl, sb + j + 4), w5 = __shfl(wl, sb + j + 5);
            float w6 = __shfl(wl, sb + j + 6), w7 = __shfl(wl, sb + j + 7);
            int u0 = (int)hF8[c0 * 16 + gl];
            int u1 = (int)hF8[c1 * 16 + gl];
            int u2 = (int)hF8[c2 * 16 + gl];
            int u3 = (int)hF8[c3 * 16 + gl];
            int u4 = (int)hF8[c4 * 16 + gl];
            int u5 = (int)hF8[c5 * 16 + gl];
            int u6 = (int)hF8[c6 * 16 + gl];
            int u7 = (int)hF8[c7 * 16 + gl];
            a0 += w0 * __builtin_amdgcn_cvt_f32_fp8(u0, 0);
            a1 += w0 * __builtin_amdgcn_cvt_f32_fp8(u0, 1);
            a2 += w0 * __builtin_amdgcn_cvt_f32_fp8(u0, 2);
            a3 += w0 * __builtin_amdgcn_cvt_f32_fp8(u0, 3);
            a0 += w1 * __builtin_amdgcn_cvt_f32_fp8(u1, 0);
            a1 += w1 * __builtin_amdgcn_cvt_f32_fp8(u1, 1);
            a2 += w1 * __builtin_amdgcn_cvt_f32_fp8(u1, 2);
            a3 += w1 * __builtin_amdgcn_cvt_f32_fp8(u1, 3);
            a0 += w2 * __builtin_amdgcn_cvt_f32_fp8(u2, 0);
            a1 += w2 * __builtin_amdgcn_cvt_f32_fp8(u2, 1);
            a2 += w2 * __builtin_amdgcn_cvt_f32_fp8(u2, 2);
            a3 += w2 * __builtin_amdgcn_cvt_f32_fp8(u2, 3);
            a0 += w3 * __builtin_amdgcn_cvt_f32_fp8(u3, 0);
            a1 += w3 * __builtin_amdgcn_cvt_f32_fp8(u3, 1);
            a2 += w3 * __builtin_amdgcn_cvt_f32_fp8(u3, 2);
            a3 += w3 * __builtin_amdgcn_cvt_f32_fp8(u3, 3);
            a0 += w4 * __builtin_amdgcn_cvt_f32_fp8(u4, 0);
            a1 += w4 * __builtin_amdgcn_cvt_f32_fp8(u4, 1);
            a2 += w4 * __builtin_amdgcn_cvt_f32_fp8(u4, 2);
            a3 += w4 * __builtin_amdgcn_cvt_f32_fp8(u4, 3);
            a0 += w5 * __builtin_amdgcn_cvt_f32_fp8(u5, 0);
            a1 += w5 * __builtin_amdgcn_cvt_f32_fp8(u5, 1);
            a2 += w5 * __builtin_amdgcn_cvt_f32_fp8(u5, 2);
            a3 += w5 * __builtin_amdgcn_cvt_f32_fp8(u5, 3);
            a0 += w6 * __builtin_amdgcn_cvt_f32_fp8(u6, 0);
            a1 += w6 * __builtin_amdgcn_cvt_f32_fp8(u6, 1);
            a2 += w6 * __builtin_amdgcn_cvt_f32_fp8(u6, 2);
            a3 += w6 * __builtin_amdgcn_cvt_f32_fp8(u6, 3);
            a0 += w7 * __builtin_amdgcn_cvt_f32_fp8(u7, 0);
            a1 += w7 * __builtin_amdgcn_cvt_f32_fp8(u7, 1);
            a2 += w7 * __builtin_amdgcn_cvt_f32_fp8(u7, 2);
            a3 += w7 * __builtin_amdgcn_cvt_f32_fp8(u7, 3);
        }
        for (; j < cnt; j++) {
            int   c = __shfl(cl, sb + j);
            float w = __shfl(wl, sb + j);
            int u = (int)hF8[c * 16 + gl];
            a0 += w * __builtin_amdgcn_cvt_f32_fp8(u, 0);
            a1 += w * __builtin_amdgcn_cvt_f32_fp8(u, 1);
            a2 += w * __builtin_amdgcn_cvt_f32_fp8(u, 2);
            a3 += w * __builtin_amdgcn_cvt_f32_fp8(u, 3);
        }
    }
    if (row < N)
        h2F8[row * 16 + gl] = fp8pack4(fmaxf(a0, 0.f), fmaxf(a1, 0.f),
                                       fmaxf(a2, 0.f), fmaxf(a3, 0.f));
}

// Dense: z = relu_h2 @ W2 + b2, fp8 out. R17 memory shape (32 rows/wave,
// 16 scalar dword loads/row, byte store) + 4 independent acc chains —
// ONLY the accumulation register assignment differs from R17.
__global__ void dense_kernel(const unsigned* h2F8, const void* W2, const void* b2,
                             unsigned char* zb, const int* flags, int N) {
    int bf16 = flags[0];
    int wave = (int)((blockIdx.x * blockDim.x + threadIdx.x) >> 6);
    int lane = threadIdx.x & 63;
    int jj = (lane < LAB) ? lane : 0;
    float w2c[HID];
#pragma unroll
    for (int k = 0; k < HID; k++) w2c[k] = loadF(W2, (size_t)k * LAB + jj, bf16);
    float bias = loadF(b2, (size_t)jj, bf16);
    int r0 = wave * 32;
    int r1 = min(r0 + 32, N);
    for (int r = r0; r < r1; r++) {
        const unsigned* hr = h2F8 + (size_t)r * 16;
        float acc0 = bias, acc1 = 0.f, acc2 = 0.f, acc3 = 0.f;
#pragma unroll
        for (int k16 = 0; k16 < 16; k16 += 4) {
            int d0 = (int)hr[k16];
            int d1 = (int)hr[k16 + 1];
            int d2 = (int)hr[k16 + 2];
            int d3 = (int)hr[k16 + 3];
            acc0 += __builtin_amdgcn_cvt_f32_fp8(d0, 0) * w2c[4 * k16];
            acc0 += __builtin_amdgcn_cvt_f32_fp8(d0, 1) * w2c[4 * k16 + 1];
            acc0 += __builtin_amdgcn_cvt_f32_fp8(d0, 2) * w2c[4 * k16 + 2];
            acc0 += __builtin_amdgcn_cvt_f32_fp8(d0, 3) * w2c[4 * k16 + 3];
            acc1 += __builtin_amdgcn_cvt_f32_fp8(d1, 0) * w2c[4 * k16 + 4];
            acc1 += __builtin_amdgcn_cvt_f32_fp8(d1, 1) * w2c[4 * k16 + 5];
            acc1 += __builtin_amdgcn_cvt_f32_fp8(d1, 2) * w2c[4 * k16 + 6];
            acc1 += __builtin_amdgcn_cvt_f32_fp8(d1, 3) * w2c[4 * k16 + 7];
            acc2 += __builtin_amdgcn_cvt_f32_fp8(d2, 0) * w2c[4 * k16 + 8];
            acc2 += __builtin_amdgcn_cvt_f32_fp8(d2, 1) * w2c[4 * k16 + 9];
            acc2 += __builtin_amdgcn_cvt_f32_fp8(d2, 2) * w2c[4 * k16 + 10];
            acc2 += __builtin_amdgcn_cvt_f32_fp8(d2, 3) * w2c[4 * k16 + 11];
            acc3 += __builtin_amdgcn_cvt_f32_fp8(d3, 0) * w2c[4 * k16 + 12];
            acc3 += __builtin_amdgcn_cvt_f32_fp8(d3, 1) * w2c[4 * k16 + 13];
            acc3 += __builtin_amdgcn_cvt_f32_fp8(d3, 2) * w2c[4 * k16 + 14];
            acc3 += __builtin_amdgcn_cvt_f32_fp8(d3, 3) * w2c[4 * k16 + 15];
        }
        float acc = (acc0 + acc1) + (acc2 + acc3);
        if (lane < LAB) {
            int pk = __builtin_amdgcn_cvt_pk_fp8_f32(acc, acc, 0, false);
            zb[(size_t)r * LAB + lane] = (unsigned char)(pk & 0xFF);
        }
    }
}

// 4 rows/wave: z2 = A@z (fp8 gather), fused log_softmax -> out.
__global__ void gather_edge_lsm_kernel(const int* rp, const int2* P,
                                       const unsigned* zF8, void* out,
                                       const int* flags, int N) {
    int bf16 = flags[0];
    int wave = (blockIdx.x * blockDim.x + threadIdx.x) >> 6;
    int lane = threadIdx.x & 63;
    int g = lane >> 4, gl = lane & 15;
    int row = 4 * wave + g;
    int s = 0, e = 0;
    if (row < N) { s = rp[N + row]; e = rp[N + row + 1]; }
    float a0 = 0.f, a1 = 0.f, a2 = 0.f, a3 = 0.f;
    const int sb = g << 4;
    const int act = (gl < 10);
    for (int base = s; base < e; base += 16) {
        int idx = base + gl;
        int cl = 0; float wl = 0.f;
        if (idx < e) ntload(P, idx, &cl, &wl);
        int cnt = min(16, e - base);
        int j = 0;
        for (; j + 4 <= cnt; j += 4) {
            int   c0 = __shfl(cl, sb + j),     c1 = __shfl(cl, sb + j + 1);
            int   c2 = __shfl(cl, sb + j + 2), c3 = __shfl(cl, sb + j + 3);
            float w0 = __shfl(wl, sb + j),     w1 = __shfl(wl, sb + j + 1);
            float w2 = __shfl(wl, sb + j + 2), w3 = __shfl(wl, sb + j + 3);
            if (act) {
                int u0 = (int)zF8[c0 * 10 + gl];
                int u1 = (int)zF8[c1 * 10 + gl];
                int u2 = (int)zF8[c2 * 10 + gl];
                int u3 = (int)zF8[c3 * 10 + gl];
                a0 += w0 * __builtin_amdgcn_cvt_f32_fp8(u0, 0);
                a1 += w0 * __builtin_amdgcn_cvt_f32_fp8(u0, 1);
                a2 += w0 * __builtin_amdgcn_cvt_f32_fp8(u0, 2);
                a3 += w0 * __builtin_amdgcn_cvt_f32_fp8(u0, 3);
                a0 += w1 * __builtin_amdgcn_cvt_f32_fp8(u1, 0);
                a1 += w1 * __builtin_amdgcn_cvt_f32_fp8(u1, 1);
                a2 += w1 * __builtin_amdgcn_cvt_f32_fp8(u1, 2);
                a3 += w1 * __builtin_amdgcn_cvt_f32_fp8(u1, 3);
                a0 += w2 * __builtin_amdgcn_cvt_f32_fp8(u2, 0);
                a1 += w2 * __builtin_amdgcn_cvt_f32_fp8(u2, 1);
                a2 += w2 * __builtin_amdgcn_cvt_f32_fp8(u2, 2);
                a3 += w2 * __builtin_amdgcn_cvt_f32_fp8(u2, 3);
                a0 += w3 * __builtin_amdgcn_cvt_f32_fp8(u3, 0);
                a1 += w3 * __builtin_amdgcn_cvt_f32_fp8(u3, 1);
                a2 += w3 * __builtin_amdgcn_cvt_f32_fp8(u3, 2);
                a3 += w3 * __builtin_amdgcn_cvt_f32_fp8(u3, 3);
            }
        }
        for (; j < cnt; j++) {
            int   c = __shfl(cl, sb + j);
            float w = __shfl(wl, sb + j);
            if (act) {
                int u = (int)zF8[c * 10 + gl];
                a0 += w * __builtin_amdgcn_cvt_f32_fp8(u, 0);
                a1 += w * __builtin_amdgcn_cvt_f32_fp8(u, 1);
                a2 += w * __builtin_amdgcn_cvt_f32_fp8(u, 2);
                a3 += w * __builtin_amdgcn_cvt_f32_fp8(u, 3);
            }
        }
    }
    float m = act ? fmaxf(fmaxf(a0, a1), fmaxf(a2, a3)) : -INFINITY;
#pragma unroll
    for (int off = 8; off; off >>= 1) m = fmaxf(m, __shfl_xor(m, off));
    float es = act ? (__expf(a0 - m) + __expf(a1 - m) + __expf(a2 - m) + __expf(a3 - m)) : 0.f;
#pragma unroll
    for (int off = 8; off; off >>= 1) es += __shfl_xor(es, off);
    float lse = m + __logf(es);
    if (act && row < N) {
        float o0 = a0 - lse, o1 = a1 - lse, o2 = a2 - lse, o3 = a3 - lse;
        if (bf16) {
            ((uint2*)out)[(size_t)row * 10 + gl] =
                make_uint2(bfpack(o0, o1), bfpack(o2, o3));
        } else {
            float4 v = make_float4(o0, o1, o2, o3);
            ((float4*)out)[(size_t)row * 10 + gl] = v;
        }
    }
}

extern "C" void kernel_launch(void* const* d_in, const int* in_sizes, int n_in,
                              void* d_out, int out_size, void* d_ws, size_t ws_size,
                              hipStream_t stream) {
    const void* fidx = d_in[0];
    const void* fval = d_in[1];
    const void* eidx = d_in[2];
    const void* ew   = d_in[3];
    const void* W1   = d_in[4];
    const void* b1   = d_in[5];
    const void* W2   = d_in[6];
    const void* b2   = d_in[7];

    const int nnz = in_sizes[1];          // 2,500,000
    const int nW1 = in_sizes[4];          // 2048*64
    const int nE  = in_sizes[3];          // 1,700,000
    const int N   = out_size / LAB;       // 100,000
    const int M   = 2 * N;
    const int nT  = nnz + nE;
    const int K   = (M + (1 << RSH) - 1) >> RSH;   // 391 buckets
    const int NBLK = (nT + TILE_A - 1) / TILE_A;   // 586 tile blocks

    auto align256 = [](size_t x) { return (x + 255) & ~(size_t)255; };
    char* ws = (char*)d_ws;
    size_t off = 0;
    int*   flags   = (int*)(ws + off);   off += 256;
    // front: hF8 (6.4MB) | h2F8 (6.4MB) | zF8 (4MB); Q (int2, 33.6MB) overlays
    // front and dies before gather_feat writes hF8.
    char*  front   = ws + off;
    unsigned* hF8  = (unsigned*)front;                       // N*16 dwords
    unsigned* h2F8 = hF8 + (size_t)N * 16;                   // N*16 dwords
    unsigned char* zb = (unsigned char*)(h2F8 + (size_t)N * 16);  // N*40 B
    size_t frontBytes = (size_t)N * (64 + 64 + 40);
    size_t qBytes     = (size_t)nT * 8;
    off += align256(frontBytes > qBytes ? frontBytes : qBytes);
    int2*  P       = (int2*)(ws + off);  off += align256((size_t)nT * 8);
    int*   rp      = (int*)(ws + off);   off += align256(((size_t)KMAX << RSH) * 4 + 16);
    uint2* w1q     = (uint2*)(ws + off); off += align256((size_t)nW1 * 2);
    int*   cntB    = (int*)(ws + off);   off += KMAX * 4;
    int*   bqstart = (int*)(ws + off);   off += KMAX * 4;
    int*   cntPB   = (int*)(ws + off);   off += align256((size_t)KMAX * NBLK * 4);
    int2*  Q       = (int2*)front;

    // 1. dtype probe
    probe_kernel<<<1, 64, 0, stream>>>(b1, fidx, flags);

    // 2. zero bucket histogram; stage W1 packed
    zero_kernel<<<1, 256, 0, stream>>>((int4*)cntB, KMAX / 4);
    convw1_kernel<<<(nW1 / 4 + 255) / 256, 256, 0, stream>>>(W1, w1q, flags, nW1 / 4);

    // 3. bucket histogram, tiled like bucketA -> per-(bucket,block) counts
    histB_kernel<<<NBLK, 1024, 0, stream>>>(fidx, eidx, cntB, cntPB,
                                            flags, nnz, nE, N, NBLK);

    // 4. bucket scan -> bucket starts
    scanB_kernel<<<1, KMAX, 0, stream>>>(cntB, bqstart, K);

    // 5. per-bucket scan over blocks -> absolute write base per (bucket,block)
    scanPB_kernel<<<K, 1024, 0, stream>>>(cntPB, bqstart, NBLK);

    // 6. pass A: register tile -> LDS bucket-sort -> coalesced scatter into Q
    bucketA_kernel<<<NBLK, 1024, 0, stream>>>(fidx, fval, eidx, ew, flags,
                                              cntPB, Q, nnz, nE, N, NBLK);

    // 7. pass B: per-bucket row hist/scan in LDS, rp segment, scatter -> P
    bucketB_kernel<<<K, 1024, 0, stream>>>(Q, bqstart, rp, P, nT, K);

    // 8. h = sparse_features @ W1 + b1 -> fp8
    int nwaves = (N + 3) / 4;
    int gblocks = (int)(((size_t)nwaves * 64 + 255) / 256);
    gather_feat_kernel<<<gblocks, 256, 0, stream>>>(rp, P, w1q, b1, hF8, flags, N);

    // 9. h2 = relu(A @ h) -> fp8 (gather-only, no epilogue)
    gather_edge_h2_kernel<<<gblocks, 256, 0, stream>>>(rp, P, hF8, h2F8, N);

    // 10. z = h2 @ W2 + b2 -> fp8 (R17 shape + 4 acc chains)
    int dwaves = (N + 31) / 32;
    int dblocks = (dwaves * 64 + 255) / 256;
    dense_kernel<<<dblocks, 256, 0, stream>>>(h2F8, W2, b2, zb, flags, N);

    // 11. out = log_softmax(A @ z)
    gather_edge_lsm_kernel<<<gblocks, 256, 0, stream>>>(rp, P, (const unsigned*)zb,
                                                        d_out, flags, N);
}

// Round 7
// 304.099 us; speedup vs baseline: 1.2831x; 1.2447x over previous
//
#include <hip/hip_runtime.h>
#include <hip/hip_bf16.h>

// ---------------------------------------------------------------------------
// GCN forward on MI355X — round 20.
// R18/R19 post-mortem: two micro-variants of scalar dense both regressed
// (50 -> 101 / 88us) via codegen-level load reordering (FETCH/WRITE blowup).
// Scalar dense is a fragile local optimum 25x off its ~2us HBM roofline.
// R20: dense becomes an MFMA GEMM (M=100K,K=64,N=40->48):
//   - one wave per 16-row tile, 6x mfma_f32_16x16x32_bf16 (3 N-tiles x K=64/32)
//   - A-frag: uint2 from h2F8, fp8->bf16 cvt (exact); layout row=l&15,
//     k=(l>>4)*8+q (AMD-documented, env-verified)
//   - B-frag: W2 pre-swizzled to fragment layout in bf16 by convw2 (6KB)
//   - bias in C init (col-only); D: row=(l>>4)*4+reg, col=l&15 (m89-verified)
// Everything else identical to R17 (bucketA parked at 50us).
// Predicted: dense 50 -> 6-12us, MfmaUtil nonzero; total ~295-300us.
// ---------------------------------------------------------------------------

#define HID 64
#define LAB 40
#define RSH 9          // 512 rows per bucket
#define KMAX 512       // max buckets (runtime K = 391)
#define TILE_A 7168    // elements per tile block (1024 threads x 7)
#define EPT 7          // elements per thread in bucketA/histB

typedef __attribute__((ext_vector_type(8))) short short8;
typedef __attribute__((ext_vector_type(4))) float f32x4;

__device__ __forceinline__ float loadF(const void* p, size_t i, int bf16) {
    if (bf16) return __bfloat162float(((const __hip_bfloat16*)p)[i]);
    return ((const float*)p)[i];
}

__device__ __forceinline__ int loadI(const void* p, size_t i, int i64) {
    if (i64) return (int)(((const long long*)p)[i]);
    return ((const int*)p)[i];
}

// packed bf16x2 helpers
__device__ __forceinline__ float bflo(unsigned v) { return __uint_as_float(v << 16); }
__device__ __forceinline__ float bfhi(unsigned v) { return __uint_as_float(v & 0xFFFF0000u); }
__device__ __forceinline__ unsigned bfr16(float x) {
    unsigned u = __float_as_uint(x);
    return (u + 0x7FFFu + ((u >> 16) & 1u)) >> 16;
}
__device__ __forceinline__ unsigned bfpack(float lo, float hi) {
    return bfr16(lo) | (bfr16(hi) << 16);
}

// fp8 e4m3 HW converts
__device__ __forceinline__ unsigned fp8pack4(float a, float b, float c, float d) {
    int r = __builtin_amdgcn_cvt_pk_fp8_f32(a, b, 0, false);
    r = __builtin_amdgcn_cvt_pk_fp8_f32(c, d, r, true);
    return (unsigned)r;
}

// nontemporal int2 load (keep P streams out of L2)
__device__ __forceinline__ void ntload(const int2* P, int idx, int* c, float* w) {
    long long raw = __builtin_nontemporal_load((const long long*)P + idx);
    *c = (int)(unsigned)(raw & 0xFFFFFFFFll);
    *w = __int_as_float((int)(raw >> 32));
}

// 8 fp8 bytes (uint2) -> short8 of bf16 (fp8->bf16 is exact)
__device__ __forceinline__ short8 cvt8(uint2 u) {
    short8 r;
    r[0] = (short)bfr16(__builtin_amdgcn_cvt_f32_fp8((int)u.x, 0));
    r[1] = (short)bfr16(__builtin_amdgcn_cvt_f32_fp8((int)u.x, 1));
    r[2] = (short)bfr16(__builtin_amdgcn_cvt_f32_fp8((int)u.x, 2));
    r[3] = (short)bfr16(__builtin_amdgcn_cvt_f32_fp8((int)u.x, 3));
    r[4] = (short)bfr16(__builtin_amdgcn_cvt_f32_fp8((int)u.y, 0));
    r[5] = (short)bfr16(__builtin_amdgcn_cvt_f32_fp8((int)u.y, 1));
    r[6] = (short)bfr16(__builtin_amdgcn_cvt_f32_fp8((int)u.y, 2));
    r[7] = (short)bfr16(__builtin_amdgcn_cvt_f32_fp8((int)u.y, 3));
    return r;
}

// dtype probe (validated R1-R19)
__global__ void probe_kernel(const void* b1p, const void* fidxp, int* flags) {
    if (threadIdx.x == 0 && blockIdx.x == 0) {
        const unsigned short* u = (const unsigned short*)b1p;
        int bf16 = 1;
        for (int i = 0; i < 64; i += 2)
            if ((unsigned short)(u[i] & 0x7FFF) >= 0x3E80) { bf16 = 0; break; }
        const int* ip = (const int*)fidxp;
        int i64 = 1;
        for (int i = 1; i < 128; i += 2)
            if (ip[i] != 0) { i64 = 0; break; }
        flags[0] = bf16; flags[1] = i64; flags[2] = 0; flags[3] = 0;
    }
}

__global__ void zero_kernel(int4* p, int n4) {
    int i = blockIdx.x * blockDim.x + threadIdx.x;
    if (i < n4) p[i] = make_int4(0, 0, 0, 0);
}

// W1 -> packed bf16 staging: entry i = features 4i..4i+3 (uint2)
__global__ void convw1_kernel(const void* W1, uint2* w1q, const int* flags, int ne) {
    int i = blockIdx.x * blockDim.x + threadIdx.x;
    if (i < ne) {
        float f0 = loadF(W1, (size_t)4 * i,     flags[0]);
        float f1 = loadF(W1, (size_t)4 * i + 1, flags[0]);
        float f2 = loadF(W1, (size_t)4 * i + 2, flags[0]);
        float f3 = loadF(W1, (size_t)4 * i + 3, flags[0]);
        w1q[i] = make_uint2(bfpack(f0, f1), bfpack(f2, f3));
    }
}

// W2 -> MFMA B-fragment staging (bf16). Frag (t, kh): lane holds
// B[k = kh*32 + (lane>>4)*8 + q][col = t*16 + (lane&15)], q=0..7, 0-padded
// for col >= 40. One uint4 (8 bf16) per (t,kh,lane): w2f[(t*2+kh)*64+lane].
__global__ void convw2_kernel(const void* W2, uint4* w2f, const int* flags) {
    int tid = threadIdx.x;
    if (tid < 384) {
        int t    = tid >> 7;
        int kh   = (tid >> 6) & 1;
        int lane = tid & 63;
        int col  = t * 16 + (lane & 15);
        int kb   = kh * 32 + (lane >> 4) * 8;
        unsigned d[4];
#pragma unroll
        for (int q = 0; q < 8; q += 2) {
            float v0 = (col < LAB) ? loadF(W2, (size_t)(kb + q) * LAB + col, flags[0]) : 0.f;
            float v1 = (col < LAB) ? loadF(W2, (size_t)(kb + q + 1) * LAB + col, flags[0]) : 0.f;
            d[q >> 1] = bfpack(v0, v1);
        }
        w2f[(t * 2 + kh) * 64 + lane] = make_uint4(d[0], d[1], d[2], d[3]);
    }
}

// Bucket histogram, tiled EXACTLY like bucketA (one block per TILE_A run).
// Emits per-(bucket,block) counts cntPB[b*nblk+blk] + global totals cntB.
__global__ __launch_bounds__(1024)
void histB_kernel(const void* fidx, const void* eidx, int* cntB, int* cntPB,
                  const int* flags, int nnz, int nE, int N, int nblk) {
    __shared__ int lh[KMAX];
    if (threadIdx.x < KMAX) lh[threadIdx.x] = 0;
    __syncthreads();
    const int i64 = flags[1];
    const int nT = nnz + nE;
    const int base = blockIdx.x * TILE_A;
#pragma unroll
    for (int k = 0; k < EPT; k++) {
        int i = base + k * 1024 + threadIdx.x;
        if (i < nT) {
            int grow = (i < nnz) ? loadI(fidx, (size_t)i, i64)
                                 : N + loadI(eidx, (size_t)(i - nnz), i64);
            atomicAdd(&lh[grow >> RSH], 1);
        }
    }
    __syncthreads();
    if (threadIdx.x < KMAX) {
        int c = lh[threadIdx.x];
        cntPB[(size_t)threadIdx.x * nblk + blockIdx.x] = c;
        if (c) atomicAdd(&cntB[threadIdx.x], c);
    }
}

// single-block exclusive scan of bucket counts -> bqstart
__global__ void scanB_kernel(const int* cntB, int* bqstart, int K) {
    __shared__ int s[KMAX];
    int t = threadIdx.x;
    int x = (t < K) ? cntB[t] : 0;
    s[t] = x;
    __syncthreads();
    for (int off = 1; off < KMAX; off <<= 1) {
        int v = (t >= off) ? s[t - off] : 0;
        __syncthreads();
        s[t] += v;
        __syncthreads();
    }
    if (t < K) bqstart[t] = s[t] - x;
}

// one block per bucket: exclusive scan over the nblk per-block counts,
// rebased by bqstart -> cntPB becomes absolute write base per (bucket,block)
__global__ __launch_bounds__(1024)
void scanPB_kernel(int* cntPB, const int* bqstart, int nblk) {
    __shared__ int s[1024];
    const int b = blockIdx.x;
    const int t = threadIdx.x;
    int x = (t < nblk) ? cntPB[(size_t)b * nblk + t] : 0;
    s[t] = x;
    __syncthreads();
    for (int off = 1; off < 1024; off <<= 1) {
        int v = (t >= off) ? s[t - off] : 0;
        __syncthreads();
        s[t] += v;
        __syncthreads();
    }
    if (t < nblk) cntPB[(size_t)b * nblk + t] = bqstart[b] + s[t] - x;
}

// Pass A: register-held tile -> LDS bucket-sort -> coalesced flush to Q.
// stage 56KB + hist 2KB + lofs 2.05KB + delta 2KB = 63.5KB LDS, 2 blocks/CU.
__global__ __launch_bounds__(1024)
void bucketA_kernel(const void* fidx, const void* fval,
                    const void* eidx, const void* ew,
                    const int* flags, const int* cntPB, int2* Q,
                    int nnz, int nE, int N, int nblk) {
    __shared__ int2 stage[TILE_A];
    __shared__ int hist[KMAX];
    __shared__ int lofs[KMAX + 1];
    __shared__ int delta[KMAX];
    const int i64 = flags[1], bf16 = flags[0];
    const int nT = nnz + nE;
    const int base = blockIdx.x * TILE_A;
    const int t = threadIdx.x;
    if (t < KMAX) hist[t] = 0;
    __syncthreads();

    // phase 1: load tile into registers, LDS histogram with returned rank
    int key[EPT]; float val[EPT]; int bk[EPT]; int rk[EPT];
#pragma unroll
    for (int k = 0; k < EPT; k++) {
        int i = base + k * 1024 + t;
        bk[k] = -1; rk[k] = 0; key[k] = 0; val[k] = 0.f;
        if (i < nT) {
            int grow, c; float v;
            if (i < nnz) {
                grow = loadI(fidx, (size_t)i, i64);
                c    = loadI(fidx, (size_t)nnz + i, i64);
                v    = loadF(fval, (size_t)i, bf16);
            } else {
                int j = i - nnz;
                grow = N + loadI(eidx, (size_t)j, i64);
                c    = loadI(eidx, (size_t)nE + j, i64);
                v    = loadF(ew, (size_t)j, bf16);
            }
            int b = grow >> RSH;
            bk[k]  = b;
            key[k] = ((grow & ((1 << RSH) - 1)) << 17) | c;
            val[k] = v;
            rk[k]  = atomicAdd(&hist[b], 1);
        }
    }
    __syncthreads();

    // phase 2: inclusive scan of counts (scratch in delta), then
    // lofs = exclusive scan (+ sentinel), delta = gbase - lofs
    int cnt = (t < KMAX) ? hist[t] : 0;
    if (t < KMAX) delta[t] = cnt;
    __syncthreads();
    for (int off2 = 1; off2 < KMAX; off2 <<= 1) {
        int v2 = (t >= off2 && t < KMAX) ? delta[t - off2] : 0;
        __syncthreads();
        if (t < KMAX) delta[t] += v2;
        __syncthreads();
    }
    if (t < KMAX) {
        int incl = delta[t];
        int excl = incl - cnt;
        lofs[t] = excl;
        if (t == KMAX - 1) lofs[KMAX] = incl;
        delta[t] = cntPB[(size_t)t * nblk + blockIdx.x] - excl;
    }
    __syncthreads();

    // phase 3: stage into LDS in bucket-sorted order
#pragma unroll
    for (int k = 0; k < EPT; k++) {
        if (bk[k] >= 0)
            stage[lofs[bk[k]] + rk[k]] = make_int2(key[k], __float_as_int(val[k]));
    }
    __syncthreads();

    // phase 4: linear flush; dest(p) = delta[b(p)] + p, b via binary search
    const int total = min(TILE_A, nT - base);
    for (int p = t; p < total; p += 1024) {
        int b = 0;
#pragma unroll
        for (int step = KMAX / 2; step; step >>= 1)
            if (lofs[b + step] <= p) b += step;
        Q[delta[b] + p] = stage[p];
    }
}

// Pass B: one 1024-thread block per bucket; LDS row hist + scan -> rp segment,
// scatter to P with LDS rank cursors. Scan is 512-wide (rows/bucket), guarded.
__global__ __launch_bounds__(1024)
void bucketB_kernel(const int2* Q, const int* bqstart, int* rp,
                    int2* P, int nT, int K) {
    __shared__ int lh[1 << RSH];
    __shared__ int s[1 << RSH];
    __shared__ int lstart[1 << RSH];
    const int b = blockIdx.x;
    const int t = threadIdx.x;
    const int start = bqstart[b];
    const int end = (b == K - 1) ? nT : bqstart[b + 1];
    if (t < (1 << RSH)) lh[t] = 0;
    __syncthreads();
    for (int i = start + t; i < end; i += 1024)
        atomicAdd(&lh[((unsigned)Q[i].x) >> 17], 1);
    __syncthreads();
    int x = (t < (1 << RSH)) ? lh[t] : 0;
    if (t < (1 << RSH)) s[t] = x;
    __syncthreads();
    for (int off = 1; off < (1 << RSH); off <<= 1) {
        int v = (t >= off && t < (1 << RSH)) ? s[t - off] : 0;
        __syncthreads();
        if (t < (1 << RSH)) s[t] += v;
        __syncthreads();
    }
    if (t < (1 << RSH)) {
        int rowstart = start + s[t] - x;
        rp[(b << RSH) + t] = rowstart;
        lstart[t] = rowstart;
        lh[t] = 0;
    }
    __syncthreads();
    for (int i = start + t; i < end; i += 1024) {
        int2 el = Q[i];
        int lr = ((unsigned)el.x) >> 17;
        int rank = atomicAdd(&lh[lr], 1);
        P[lstart[lr] + rank] = make_int2(el.x & 0x1FFFF, el.y);
    }
}

// 4 rows/wave feat gather: h = b1 + sum v*W1[c], stored fp8 (row*16+gl dword).
__global__ void gather_feat_kernel(const int* rp, const int2* P,
                                   const uint2* w1q, const void* b1,
                                   unsigned* hF8, const int* flags, int N) {
    int bf16 = flags[0];
    int wave = (blockIdx.x * blockDim.x + threadIdx.x) >> 6;
    int lane = threadIdx.x & 63;
    int g = lane >> 4, gl = lane & 15;
    int row = 4 * wave + g;
    int s = 0, e = 0;
    if (row < N) { s = rp[row]; e = rp[row + 1]; }
    float a0 = loadF(b1, (size_t)4 * gl,     bf16);
    float a1 = loadF(b1, (size_t)4 * gl + 1, bf16);
    float a2 = loadF(b1, (size_t)4 * gl + 2, bf16);
    float a3 = loadF(b1, (size_t)4 * gl + 3, bf16);
    const int sb = g << 4;
    for (int base = s; base < e; base += 16) {
        int idx = base + gl;
        int cl = 0; float vl = 0.f;
        if (idx < e) ntload(P, idx, &cl, &vl);
        int cnt = min(16, e - base);
        int j = 0;
        for (; j + 4 <= cnt; j += 4) {
            int   c0 = __shfl(cl, sb + j),     c1 = __shfl(cl, sb + j + 1);
            int   c2 = __shfl(cl, sb + j + 2), c3 = __shfl(cl, sb + j + 3);
            float v0 = __shfl(vl, sb + j),     v1 = __shfl(vl, sb + j + 1);
            float v2 = __shfl(vl, sb + j + 2), v3 = __shfl(vl, sb + j + 3);
            uint2 u0 = w1q[c0 * 16 + gl];
            uint2 u1 = w1q[c1 * 16 + gl];
            uint2 u2 = w1q[c2 * 16 + gl];
            uint2 u3 = w1q[c3 * 16 + gl];
            a0 += v0 * bflo(u0.x); a1 += v0 * bfhi(u0.x);
            a2 += v0 * bflo(u0.y); a3 += v0 * bfhi(u0.y);
            a0 += v1 * bflo(u1.x); a1 += v1 * bfhi(u1.x);
            a2 += v1 * bflo(u1.y); a3 += v1 * bfhi(u1.y);
            a0 += v2 * bflo(u2.x); a1 += v2 * bfhi(u2.x);
            a2 += v2 * bflo(u2.y); a3 += v2 * bfhi(u2.y);
            a0 += v3 * bflo(u3.x); a1 += v3 * bfhi(u3.x);
            a2 += v3 * bflo(u3.y); a3 += v3 * bfhi(u3.y);
        }
        for (; j < cnt; j++) {
            int   c = __shfl(cl, sb + j);
            float v = __shfl(vl, sb + j);
            uint2 u = w1q[c * 16 + gl];
            a0 += v * bflo(u.x); a1 += v * bfhi(u.x);
            a2 += v * bflo(u.y); a3 += v * bfhi(u.y);
        }
    }
    if (row < N) hF8[row * 16 + gl] = fp8pack4(a0, a1, a2, a3);
}

// Merged propagation, NO epilogue: h2 = relu(A @ h), fp8 in / fp8 out.
__global__ void gather_edge_h2_kernel(const int* rp, const int2* P,
                                      const unsigned* hF8, unsigned* h2F8,
                                      int N) {
    int wave = (blockIdx.x * blockDim.x + threadIdx.x) >> 6;
    int lane = threadIdx.x & 63;
    int g = lane >> 4, gl = lane & 15;
    int row = 4 * wave + g;
    int s = 0, e = 0;
    if (row < N) { s = rp[N + row]; e = rp[N + row + 1]; }
    float a0 = 0.f, a1 = 0.f, a2 = 0.f, a3 = 0.f;
    const int sb = g << 4;
    for (int base = s; base < e; base += 16) {
        int idx = base + gl;
        int cl = 0; float wl = 0.f;
        if (idx < e) ntload(P, idx, &cl, &wl);
        int cnt = min(16, e - base);
        int j = 0;
        for (; j + 8 <= cnt; j += 8) {
            int   c0 = __shfl(cl, sb + j),     c1 = __shfl(cl, sb + j + 1);
            int   c2 = __shfl(cl, sb + j + 2), c3 = __shfl(cl, sb + j + 3);
            int   c4 = __shfl(cl, sb + j + 4), c5 = __shfl(cl, sb + j + 5);
            int   c6 = __shfl(cl, sb + j + 6), c7 = __shfl(cl, sb + j + 7);
            float w0 = __shfl(wl, sb + j),     w1 = __shfl(wl, sb + j + 1);
            float w2 = __shfl(wl, sb + j + 2), w3 = __shfl(wl, sb + j + 3);
            float w4 = __shfl(wl, sb + j + 4), w5 = __shfl(wl, sb + j + 5);
            float w6 = __shfl(wl, sb + j + 6), w7 = __shfl(wl, sb + j + 7);
            int u0 = (int)hF8[c0 * 16 + gl];
            int u1 = (int)hF8[c1 * 16 + gl];
            int u2 = (int)hF8[c2 * 16 + gl];
            int u3 = (int)hF8[c3 * 16 + gl];
            int u4 = (int)hF8[c4 * 16 + gl];
            int u5 = (int)hF8[c5 * 16 + gl];
            int u6 = (int)hF8[c6 * 16 + gl];
            int u7 = (int)hF8[c7 * 16 + gl];
            a0 += w0 * __builtin_amdgcn_cvt_f32_fp8(u0, 0);
            a1 += w0 * __builtin_amdgcn_cvt_f32_fp8(u0, 1);
            a2 += w0 * __builtin_amdgcn_cvt_f32_fp8(u0, 2);
            a3 += w0 * __builtin_amdgcn_cvt_f32_fp8(u0, 3);
            a0 += w1 * __builtin_amdgcn_cvt_f32_fp8(u1, 0);
            a1 += w1 * __builtin_amdgcn_cvt_f32_fp8(u1, 1);
            a2 += w1 * __builtin_amdgcn_cvt_f32_fp8(u1, 2);
            a3 += w1 * __builtin_amdgcn_cvt_f32_fp8(u1, 3);
            a0 += w2 * __builtin_amdgcn_cvt_f32_fp8(u2, 0);
            a1 += w2 * __builtin_amdgcn_cvt_f32_fp8(u2, 1);
            a2 += w2 * __builtin_amdgcn_cvt_f32_fp8(u2, 2);
            a3 += w2 * __builtin_amdgcn_cvt_f32_fp8(u2, 3);
            a0 += w3 * __builtin_amdgcn_cvt_f32_fp8(u3, 0);
            a1 += w3 * __builtin_amdgcn_cvt_f32_fp8(u3, 1);
            a2 += w3 * __builtin_amdgcn_cvt_f32_fp8(u3, 2);
            a3 += w3 * __builtin_amdgcn_cvt_f32_fp8(u3, 3);
            a0 += w4 * __builtin_amdgcn_cvt_f32_fp8(u4, 0);
            a1 += w4 * __builtin_amdgcn_cvt_f32_fp8(u4, 1);
            a2 += w4 * __builtin_amdgcn_cvt_f32_fp8(u4, 2);
            a3 += w4 * __builtin_amdgcn_cvt_f32_fp8(u4, 3);
            a0 += w5 * __builtin_amdgcn_cvt_f32_fp8(u5, 0);
            a1 += w5 * __builtin_amdgcn_cvt_f32_fp8(u5, 1);
            a2 += w5 * __builtin_amdgcn_cvt_f32_fp8(u5, 2);
            a3 += w5 * __builtin_amdgcn_cvt_f32_fp8(u5, 3);
            a0 += w6 * __builtin_amdgcn_cvt_f32_fp8(u6, 0);
            a1 += w6 * __builtin_amdgcn_cvt_f32_fp8(u6, 1);
            a2 += w6 * __builtin_amdgcn_cvt_f32_fp8(u6, 2);
            a3 += w6 * __builtin_amdgcn_cvt_f32_fp8(u6, 3);
            a0 += w7 * __builtin_amdgcn_cvt_f32_fp8(u7, 0);
            a1 += w7 * __builtin_amdgcn_cvt_f32_fp8(u7, 1);
            a2 += w7 * __builtin_amdgcn_cvt_f32_fp8(u7, 2);
            a3 += w7 * __builtin_amdgcn_cvt_f32_fp8(u7, 3);
        }
        for (; j < cnt; j++) {
            int   c = __shfl(cl, sb + j);
            float w = __shfl(wl, sb + j);
            int u = (int)hF8[c * 16 + gl];
            a0 += w * __builtin_amdgcn_cvt_f32_fp8(u, 0);
            a1 += w * __builtin_amdgcn_cvt_f32_fp8(u, 1);
            a2 += w * __builtin_amdgcn_cvt_f32_fp8(u, 2);
            a3 += w * __builtin_amdgcn_cvt_f32_fp8(u, 3);
        }
    }
    if (row < N)
        h2F8[row * 16 + gl] = fp8pack4(fmaxf(a0, 0.f), fmaxf(a1, 0.f),
                                       fmaxf(a2, 0.f), fmaxf(a3, 0.f));
}

// Dense via MFMA: z = relu_h2 @ W2 + b2, fp8 out. One wave per 16-row tile.
// A: h2 rows as bf16 (fp8->bf16 exact); B: pre-swizzled W2 frags; bias in C.
__global__ void dense_mfma_kernel(const unsigned* h2F8, const uint4* w2f,
                                  const void* b2, unsigned char* zb,
                                  const int* flags, int N) {
    int bf16 = flags[0];
    int wid  = (int)((blockIdx.x * blockDim.x + threadIdx.x) >> 6);
    int lane = threadIdx.x & 63;
    int ntiles = (N + 15) >> 4;
    if (wid >= ntiles) return;
    const int g = lane >> 4;
    const int fr = lane & 15;

    // A fragments: row = wid*16 + fr, k = kh*32 + g*8 + q
    int arow = wid * 16 + fr;
    const uint2* hrow = (const uint2*)(h2F8 + (size_t)arow * 16);
    short8 af0 = cvt8(hrow[g]);        // kh=0: dwords 2g,2g+1
    short8 af1 = cvt8(hrow[4 + g]);    // kh=1: dwords 8+2g,8+2g+1

    // B fragments + bias-initialized accumulators
    f32x4 acc[3];
#pragma unroll
    for (int t = 0; t < 3; t++) {
        int col = t * 16 + fr;
        float bias = (col < LAB) ? loadF(b2, (size_t)col, bf16) : 0.f;
        acc[t][0] = bias; acc[t][1] = bias; acc[t][2] = bias; acc[t][3] = bias;
        uint4 b0 = w2f[(t * 2 + 0) * 64 + lane];
        uint4 b1 = w2f[(t * 2 + 1) * 64 + lane];
        acc[t] = __builtin_amdgcn_mfma_f32_16x16x32_bf16(
            af0, *(short8*)&b0, acc[t], 0, 0, 0);
        acc[t] = __builtin_amdgcn_mfma_f32_16x16x32_bf16(
            af1, *(short8*)&b1, acc[t], 0, 0, 0);
    }

    // epilogue: D row = wid*16 + g*4 + q, col = t*16 + fr
#pragma unroll
    for (int t = 0; t < 3; t++) {
        int col = t * 16 + fr;
        if (col < LAB) {
#pragma unroll
            for (int q = 0; q < 4; q++) {
                int orow = wid * 16 + g * 4 + q;
                if (orow < N) {
                    int pk = __builtin_amdgcn_cvt_pk_fp8_f32(acc[t][q], acc[t][q], 0, false);
                    zb[(size_t)orow * LAB + col] = (unsigned char)(pk & 0xFF);
                }
            }
        }
    }
}

// 4 rows/wave: z2 = A@z (fp8 gather), fused log_softmax -> out.
__global__ void gather_edge_lsm_kernel(const int* rp, const int2* P,
                                       const unsigned* zF8, void* out,
                                       const int* flags, int N) {
    int bf16 = flags[0];
    int wave = (blockIdx.x * blockDim.x + threadIdx.x) >> 6;
    int lane = threadIdx.x & 63;
    int g = lane >> 4, gl = lane & 15;
    int row = 4 * wave + g;
    int s = 0, e = 0;
    if (row < N) { s = rp[N + row]; e = rp[N + row + 1]; }
    float a0 = 0.f, a1 = 0.f, a2 = 0.f, a3 = 0.f;
    const int sb = g << 4;
    const int act = (gl < 10);
    for (int base = s; base < e; base += 16) {
        int idx = base + gl;
        int cl = 0; float wl = 0.f;
        if (idx < e) ntload(P, idx, &cl, &wl);
        int cnt = min(16, e - base);
        int j = 0;
        for (; j + 4 <= cnt; j += 4) {
            int   c0 = __shfl(cl, sb + j),     c1 = __shfl(cl, sb + j + 1);
            int   c2 = __shfl(cl, sb + j + 2), c3 = __shfl(cl, sb + j + 3);
            float w0 = __shfl(wl, sb + j),     w1 = __shfl(wl, sb + j + 1);
            float w2 = __shfl(wl, sb + j + 2), w3 = __shfl(wl, sb + j + 3);
            if (act) {
                int u0 = (int)zF8[c0 * 10 + gl];
                int u1 = (int)zF8[c1 * 10 + gl];
                int u2 = (int)zF8[c2 * 10 + gl];
                int u3 = (int)zF8[c3 * 10 + gl];
                a0 += w0 * __builtin_amdgcn_cvt_f32_fp8(u0, 0);
                a1 += w0 * __builtin_amdgcn_cvt_f32_fp8(u0, 1);
                a2 += w0 * __builtin_amdgcn_cvt_f32_fp8(u0, 2);
                a3 += w0 * __builtin_amdgcn_cvt_f32_fp8(u0, 3);
                a0 += w1 * __builtin_amdgcn_cvt_f32_fp8(u1, 0);
                a1 += w1 * __builtin_amdgcn_cvt_f32_fp8(u1, 1);
                a2 += w1 * __builtin_amdgcn_cvt_f32_fp8(u1, 2);
                a3 += w1 * __builtin_amdgcn_cvt_f32_fp8(u1, 3);
                a0 += w2 * __builtin_amdgcn_cvt_f32_fp8(u2, 0);
                a1 += w2 * __builtin_amdgcn_cvt_f32_fp8(u2, 1);
                a2 += w2 * __builtin_amdgcn_cvt_f32_fp8(u2, 2);
                a3 += w2 * __builtin_amdgcn_cvt_f32_fp8(u2, 3);
                a0 += w3 * __builtin_amdgcn_cvt_f32_fp8(u3, 0);
                a1 += w3 * __builtin_amdgcn_cvt_f32_fp8(u3, 1);
                a2 += w3 * __builtin_amdgcn_cvt_f32_fp8(u3, 2);
                a3 += w3 * __builtin_amdgcn_cvt_f32_fp8(u3, 3);
            }
        }
        for (; j < cnt; j++) {
            int   c = __shfl(cl, sb + j);
            float w = __shfl(wl, sb + j);
            if (act) {
                int u = (int)zF8[c * 10 + gl];
                a0 += w * __builtin_amdgcn_cvt_f32_fp8(u, 0);
                a1 += w * __builtin_amdgcn_cvt_f32_fp8(u, 1);
                a2 += w * __builtin_amdgcn_cvt_f32_fp8(u, 2);
                a3 += w * __builtin_amdgcn_cvt_f32_fp8(u, 3);
            }
        }
    }
    float m = act ? fmaxf(fmaxf(a0, a1), fmaxf(a2, a3)) : -INFINITY;
#pragma unroll
    for (int off = 8; off; off >>= 1) m = fmaxf(m, __shfl_xor(m, off));
    float es = act ? (__expf(a0 - m) + __expf(a1 - m) + __expf(a2 - m) + __expf(a3 - m)) : 0.f;
#pragma unroll
    for (int off = 8; off; off >>= 1) es += __shfl_xor(es, off);
    float lse = m + __logf(es);
    if (act && row < N) {
        float o0 = a0 - lse, o1 = a1 - lse, o2 = a2 - lse, o3 = a3 - lse;
        if (bf16) {
            ((uint2*)out)[(size_t)row * 10 + gl] =
                make_uint2(bfpack(o0, o1), bfpack(o2, o3));
        } else {
            float4 v = make_float4(o0, o1, o2, o3);
            ((float4*)out)[(size_t)row * 10 + gl] = v;
        }
    }
}

extern "C" void kernel_launch(void* const* d_in, const int* in_sizes, int n_in,
                              void* d_out, int out_size, void* d_ws, size_t ws_size,
                              hipStream_t stream) {
    const void* fidx = d_in[0];
    const void* fval = d_in[1];
    const void* eidx = d_in[2];
    const void* ew   = d_in[3];
    const void* W1   = d_in[4];
    const void* b1   = d_in[5];
    const void* W2   = d_in[6];
    const void* b2   = d_in[7];

    const int nnz = in_sizes[1];          // 2,500,000
    const int nW1 = in_sizes[4];          // 2048*64
    const int nE  = in_sizes[3];          // 1,700,000
    const int N   = out_size / LAB;       // 100,000
    const int M   = 2 * N;
    const int nT  = nnz + nE;
    const int K   = (M + (1 << RSH) - 1) >> RSH;   // 391 buckets
    const int NBLK = (nT + TILE_A - 1) / TILE_A;   // 586 tile blocks

    auto align256 = [](size_t x) { return (x + 255) & ~(size_t)255; };
    char* ws = (char*)d_ws;
    size_t off = 0;
    int*   flags   = (int*)(ws + off);   off += 256;
    // front: hF8 (6.4MB) | h2F8 (6.4MB) | zF8 (4MB); Q (int2, 33.6MB) overlays
    // front and dies before gather_feat writes hF8.
    char*  front   = ws + off;
    unsigned* hF8  = (unsigned*)front;                       // N*16 dwords
    unsigned* h2F8 = hF8 + (size_t)N * 16;                   // N*16 dwords
    unsigned char* zb = (unsigned char*)(h2F8 + (size_t)N * 16);  // N*40 B
    size_t frontBytes = (size_t)N * (64 + 64 + 40);
    size_t qBytes     = (size_t)nT * 8;
    off += align256(frontBytes > qBytes ? frontBytes : qBytes);
    int2*  P       = (int2*)(ws + off);  off += align256((size_t)nT * 8);
    int*   rp      = (int*)(ws + off);   off += align256(((size_t)KMAX << RSH) * 4 + 16);
    uint2* w1q     = (uint2*)(ws + off); off += align256((size_t)nW1 * 2);
    uint4* w2f     = (uint4*)(ws + off); off += align256((size_t)384 * 16);
    int*   cntB    = (int*)(ws + off);   off += KMAX * 4;
    int*   bqstart = (int*)(ws + off);   off += KMAX * 4;
    int*   cntPB   = (int*)(ws + off);   off += align256((size_t)KMAX * NBLK * 4);
    int2*  Q       = (int2*)front;

    // 1. dtype probe
    probe_kernel<<<1, 64, 0, stream>>>(b1, fidx, flags);

    // 2. zero bucket histogram; stage W1 packed + W2 MFMA fragments
    zero_kernel<<<1, 256, 0, stream>>>((int4*)cntB, KMAX / 4);
    convw1_kernel<<<(nW1 / 4 + 255) / 256, 256, 0, stream>>>(W1, w1q, flags, nW1 / 4);
    convw2_kernel<<<1, 384, 0, stream>>>(W2, w2f, flags);

    // 3. bucket histogram, tiled like bucketA -> per-(bucket,block) counts
    histB_kernel<<<NBLK, 1024, 0, stream>>>(fidx, eidx, cntB, cntPB,
                                            flags, nnz, nE, N, NBLK);

    // 4. bucket scan -> bucket starts
    scanB_kernel<<<1, KMAX, 0, stream>>>(cntB, bqstart, K);

    // 5. per-bucket scan over blocks -> absolute write base per (bucket,block)
    scanPB_kernel<<<K, 1024, 0, stream>>>(cntPB, bqstart, NBLK);

    // 6. pass A: register tile -> LDS bucket-sort -> coalesced scatter into Q
    bucketA_kernel<<<NBLK, 1024, 0, stream>>>(fidx, fval, eidx, ew, flags,
                                              cntPB, Q, nnz, nE, N, NBLK);

    // 7. pass B: per-bucket row hist/scan in LDS, rp segment, scatter -> P
    bucketB_kernel<<<K, 1024, 0, stream>>>(Q, bqstart, rp, P, nT, K);

    // 8. h = sparse_features @ W1 + b1 -> fp8
    int nwaves = (N + 3) / 4;
    int gblocks = (int)(((size_t)nwaves * 64 + 255) / 256);
    gather_feat_kernel<<<gblocks, 256, 0, stream>>>(rp, P, w1q, b1, hF8, flags, N);

    // 9. h2 = relu(A @ h) -> fp8 (gather-only, no epilogue)
    gather_edge_h2_kernel<<<gblocks, 256, 0, stream>>>(rp, P, hF8, h2F8, N);

    // 10. z = h2 @ W2 + b2 -> fp8 via MFMA (one wave per 16-row tile)
    int ntiles = (N + 15) / 16;
    int dblocks = (int)(((size_t)ntiles * 64 + 255) / 256);
    dense_mfma_kernel<<<dblocks, 256, 0, stream>>>(h2F8, w2f, b2, zb, flags, N);

    // 11. out = log_softmax(A @ z)
    gather_edge_lsm_kernel<<<gblocks, 256, 0, stream>>>(rp, P, (const unsigned*)zb,
                                                        d_out, flags, N);
}

// Round 8
// 278.388 us; speedup vs baseline: 1.4016x; 1.0924x over previous
//
#include <hip/hip_runtime.h>
#include <hip/hip_bf16.h>

// ---------------------------------------------------------------------------
// GCN forward on MI355X — round 21.
// R20 post-mortem: MFMA dense WORKED (50 -> <10us, total 337->304). New top-2:
// bucketA 44.8us (parked) and bucketB 43us with WRITE 73.8MB vs 33.6 ideal
// (2.2x amp, rank-scatter into P) at 2.5TB/s = 31% peak -> plausibly
// bytes-bound. Fix: apply bucketA's LDS-staging recipe to bucketB — stage the
// bucket row-sorted in LDS, flush linearly. To fit a bucket in LDS: RSH 9->8
// (256 rows/bucket, K=782, feature-bucket mean 6400 el, CAPB=6912 = +6.4
// sigma guard w/ global-scatter fallback). bucketA/histB retile mechanically
// (KMAX=1024, TILE_A=6144). Dense MFMA + everything else frozen from R20.
// Predicted: bucketB WRITE 73.8->~34MB, dur 43->~20-26us; total ~283-288.
// ---------------------------------------------------------------------------

#define HID 64
#define LAB 40
#define RSH 8          // 256 rows per bucket
#define RPB (1 << RSH)
#define KMAX 1024      // max buckets (runtime K = 782)
#define TILE_A 6144    // elements per tile block (1024 threads x 6)
#define EPT 6          // elements per thread in bucketA/histB
#define CAPB 6912      // bucketB LDS stage capacity (mean 6400, +6.4 sigma)

typedef __attribute__((ext_vector_type(8))) short short8;
typedef __attribute__((ext_vector_type(4))) float f32x4;

__device__ __forceinline__ float loadF(const void* p, size_t i, int bf16) {
    if (bf16) return __bfloat162float(((const __hip_bfloat16*)p)[i]);
    return ((const float*)p)[i];
}

__device__ __forceinline__ int loadI(const void* p, size_t i, int i64) {
    if (i64) return (int)(((const long long*)p)[i]);
    return ((const int*)p)[i];
}

// packed bf16x2 helpers
__device__ __forceinline__ float bflo(unsigned v) { return __uint_as_float(v << 16); }
__device__ __forceinline__ float bfhi(unsigned v) { return __uint_as_float(v & 0xFFFF0000u); }
__device__ __forceinline__ unsigned bfr16(float x) {
    unsigned u = __float_as_uint(x);
    return (u + 0x7FFFu + ((u >> 16) & 1u)) >> 16;
}
__device__ __forceinline__ unsigned bfpack(float lo, float hi) {
    return bfr16(lo) | (bfr16(hi) << 16);
}

// fp8 e4m3 HW converts
__device__ __forceinline__ unsigned fp8pack4(float a, float b, float c, float d) {
    int r = __builtin_amdgcn_cvt_pk_fp8_f32(a, b, 0, false);
    r = __builtin_amdgcn_cvt_pk_fp8_f32(c, d, r, true);
    return (unsigned)r;
}

// nontemporal int2 load (keep P streams out of L2)
__device__ __forceinline__ void ntload(const int2* P, int idx, int* c, float* w) {
    long long raw = __builtin_nontemporal_load((const long long*)P + idx);
    *c = (int)(unsigned)(raw & 0xFFFFFFFFll);
    *w = __int_as_float((int)(raw >> 32));
}

// 8 fp8 bytes (uint2) -> short8 of bf16 (fp8->bf16 is exact)
__device__ __forceinline__ short8 cvt8(uint2 u) {
    short8 r;
    r[0] = (short)bfr16(__builtin_amdgcn_cvt_f32_fp8((int)u.x, 0));
    r[1] = (short)bfr16(__builtin_amdgcn_cvt_f32_fp8((int)u.x, 1));
    r[2] = (short)bfr16(__builtin_amdgcn_cvt_f32_fp8((int)u.x, 2));
    r[3] = (short)bfr16(__builtin_amdgcn_cvt_f32_fp8((int)u.x, 3));
    r[4] = (short)bfr16(__builtin_amdgcn_cvt_f32_fp8((int)u.y, 0));
    r[5] = (short)bfr16(__builtin_amdgcn_cvt_f32_fp8((int)u.y, 1));
    r[6] = (short)bfr16(__builtin_amdgcn_cvt_f32_fp8((int)u.y, 2));
    r[7] = (short)bfr16(__builtin_amdgcn_cvt_f32_fp8((int)u.y, 3));
    return r;
}

// dtype probe (validated R1-R20)
__global__ void probe_kernel(const void* b1p, const void* fidxp, int* flags) {
    if (threadIdx.x == 0 && blockIdx.x == 0) {
        const unsigned short* u = (const unsigned short*)b1p;
        int bf16 = 1;
        for (int i = 0; i < 64; i += 2)
            if ((unsigned short)(u[i] & 0x7FFF) >= 0x3E80) { bf16 = 0; break; }
        const int* ip = (const int*)fidxp;
        int i64 = 1;
        for (int i = 1; i < 128; i += 2)
            if (ip[i] != 0) { i64 = 0; break; }
        flags[0] = bf16; flags[1] = i64; flags[2] = 0; flags[3] = 0;
    }
}

__global__ void zero_kernel(int4* p, int n4) {
    int i = blockIdx.x * blockDim.x + threadIdx.x;
    if (i < n4) p[i] = make_int4(0, 0, 0, 0);
}

// W1 -> packed bf16 staging: entry i = features 4i..4i+3 (uint2)
__global__ void convw1_kernel(const void* W1, uint2* w1q, const int* flags, int ne) {
    int i = blockIdx.x * blockDim.x + threadIdx.x;
    if (i < ne) {
        float f0 = loadF(W1, (size_t)4 * i,     flags[0]);
        float f1 = loadF(W1, (size_t)4 * i + 1, flags[0]);
        float f2 = loadF(W1, (size_t)4 * i + 2, flags[0]);
        float f3 = loadF(W1, (size_t)4 * i + 3, flags[0]);
        w1q[i] = make_uint2(bfpack(f0, f1), bfpack(f2, f3));
    }
}

// W2 -> MFMA B-fragment staging (bf16). Frag (t, kh): lane holds
// B[k = kh*32 + (lane>>4)*8 + q][col = t*16 + (lane&15)], q=0..7, 0-padded
// for col >= 40. One uint4 (8 bf16) per (t,kh,lane): w2f[(t*2+kh)*64+lane].
__global__ void convw2_kernel(const void* W2, uint4* w2f, const int* flags) {
    int tid = threadIdx.x;
    if (tid < 384) {
        int t    = tid >> 7;
        int kh   = (tid >> 6) & 1;
        int lane = tid & 63;
        int col  = t * 16 + (lane & 15);
        int kb   = kh * 32 + (lane >> 4) * 8;
        unsigned d[4];
#pragma unroll
        for (int q = 0; q < 8; q += 2) {
            float v0 = (col < LAB) ? loadF(W2, (size_t)(kb + q) * LAB + col, flags[0]) : 0.f;
            float v1 = (col < LAB) ? loadF(W2, (size_t)(kb + q + 1) * LAB + col, flags[0]) : 0.f;
            d[q >> 1] = bfpack(v0, v1);
        }
        w2f[(t * 2 + kh) * 64 + lane] = make_uint4(d[0], d[1], d[2], d[3]);
    }
}

// Bucket histogram, tiled EXACTLY like bucketA (one block per TILE_A run).
// Emits per-(bucket,block) counts cntPB[b*nblk+blk] + global totals cntB.
__global__ __launch_bounds__(1024)
void histB_kernel(const void* fidx, const void* eidx, int* cntB, int* cntPB,
                  const int* flags, int nnz, int nE, int N, int nblk) {
    __shared__ int lh[KMAX];
    lh[threadIdx.x] = 0;
    __syncthreads();
    const int i64 = flags[1];
    const int nT = nnz + nE;
    const int base = blockIdx.x * TILE_A;
#pragma unroll
    for (int k = 0; k < EPT; k++) {
        int i = base + k * 1024 + threadIdx.x;
        if (i < nT) {
            int grow = (i < nnz) ? loadI(fidx, (size_t)i, i64)
                                 : N + loadI(eidx, (size_t)(i - nnz), i64);
            atomicAdd(&lh[grow >> RSH], 1);
        }
    }
    __syncthreads();
    {
        int c = lh[threadIdx.x];
        cntPB[(size_t)threadIdx.x * nblk + blockIdx.x] = c;
        if (c) atomicAdd(&cntB[threadIdx.x], c);
    }
}

// single-block exclusive scan of bucket counts -> bqstart
__global__ __launch_bounds__(1024)
void scanB_kernel(const int* cntB, int* bqstart, int K) {
    __shared__ int s[KMAX];
    int t = threadIdx.x;
    int x = (t < K) ? cntB[t] : 0;
    s[t] = x;
    __syncthreads();
    for (int off = 1; off < KMAX; off <<= 1) {
        int v = (t >= off) ? s[t - off] : 0;
        __syncthreads();
        s[t] += v;
        __syncthreads();
    }
    if (t < K) bqstart[t] = s[t] - x;
}

// one block per bucket: exclusive scan over the nblk per-block counts,
// rebased by bqstart -> cntPB becomes absolute write base per (bucket,block)
__global__ __launch_bounds__(1024)
void scanPB_kernel(int* cntPB, const int* bqstart, int nblk) {
    __shared__ int s[1024];
    const int b = blockIdx.x;
    const int t = threadIdx.x;
    int x = (t < nblk) ? cntPB[(size_t)b * nblk + t] : 0;
    s[t] = x;
    __syncthreads();
    for (int off = 1; off < 1024; off <<= 1) {
        int v = (t >= off) ? s[t - off] : 0;
        __syncthreads();
        s[t] += v;
        __syncthreads();
    }
    if (t < nblk) cntPB[(size_t)b * nblk + t] = bqstart[b] + s[t] - x;
}

// Pass A: register-held tile -> LDS bucket-sort -> coalesced flush to Q.
// stage 48KB + hist 4KB + lofs 4KB + delta 4KB = 60.5KB LDS, 2 blocks/CU.
__global__ __launch_bounds__(1024)
void bucketA_kernel(const void* fidx, const void* fval,
                    const void* eidx, const void* ew,
                    const int* flags, const int* cntPB, int2* Q,
                    int nnz, int nE, int N, int nblk) {
    __shared__ int2 stage[TILE_A];
    __shared__ int hist[KMAX];
    __shared__ int lofs[KMAX + 1];
    __shared__ int delta[KMAX];
    const int i64 = flags[1], bf16 = flags[0];
    const int nT = nnz + nE;
    const int base = blockIdx.x * TILE_A;
    const int t = threadIdx.x;
    hist[t] = 0;
    __syncthreads();

    // phase 1: load tile into registers, LDS histogram with returned rank
    int key[EPT]; float val[EPT]; int bk[EPT]; int rk[EPT];
#pragma unroll
    for (int k = 0; k < EPT; k++) {
        int i = base + k * 1024 + t;
        bk[k] = -1; rk[k] = 0; key[k] = 0; val[k] = 0.f;
        if (i < nT) {
            int grow, c; float v;
            if (i < nnz) {
                grow = loadI(fidx, (size_t)i, i64);
                c    = loadI(fidx, (size_t)nnz + i, i64);
                v    = loadF(fval, (size_t)i, bf16);
            } else {
                int j = i - nnz;
                grow = N + loadI(eidx, (size_t)j, i64);
                c    = loadI(eidx, (size_t)nE + j, i64);
                v    = loadF(ew, (size_t)j, bf16);
            }
            int b = grow >> RSH;
            bk[k]  = b;
            key[k] = ((grow & (RPB - 1)) << 17) | c;
            val[k] = v;
            rk[k]  = atomicAdd(&hist[b], 1);
        }
    }
    __syncthreads();

    // phase 2: inclusive scan of counts (scratch in delta), then
    // lofs = exclusive scan (+ sentinel), delta = gbase - lofs
    int cnt = hist[t];
    delta[t] = cnt;
    __syncthreads();
    for (int off2 = 1; off2 < KMAX; off2 <<= 1) {
        int v2 = (t >= off2) ? delta[t - off2] : 0;
        __syncthreads();
        delta[t] += v2;
        __syncthreads();
    }
    {
        int incl = delta[t];
        int excl = incl - cnt;
        lofs[t] = excl;
        if (t == KMAX - 1) lofs[KMAX] = incl;
        delta[t] = cntPB[(size_t)t * nblk + blockIdx.x] - excl;
    }
    __syncthreads();

    // phase 3: stage into LDS in bucket-sorted order
#pragma unroll
    for (int k = 0; k < EPT; k++) {
        if (bk[k] >= 0)
            stage[lofs[bk[k]] + rk[k]] = make_int2(key[k], __float_as_int(val[k]));
    }
    __syncthreads();

    // phase 4: linear flush; dest(p) = delta[b(p)] + p, b via binary search
    const int total = min(TILE_A, nT - base);
    for (int p = t; p < total; p += 1024) {
        int b = 0;
#pragma unroll
        for (int step = KMAX / 2; step; step >>= 1)
            if (lofs[b + step] <= p) b += step;
        Q[delta[b] + p] = stage[p];
    }
}

// Pass B: one 1024-thread block per bucket; LDS row hist + scan -> rp segment,
// then stage the bucket ROW-SORTED in LDS and flush linearly to P (coalesced).
// stg 55.3KB + tables 3KB = 58.3KB LDS, 2 blocks/CU. Fallback to direct
// scatter if bucket exceeds CAPB (+6.4 sigma, effectively never).
__global__ __launch_bounds__(1024)
void bucketB_kernel(const int2* Q, const int* bqstart, int* rp,
                    int2* P, int nT, int K) {
    __shared__ int2 stg[CAPB];
    __shared__ int lh[RPB];
    __shared__ int s[RPB];
    __shared__ int lstart[RPB];
    const int b = blockIdx.x;
    const int t = threadIdx.x;
    const int start = bqstart[b];
    const int end = (b == K - 1) ? nT : bqstart[b + 1];
    const int cnt = end - start;
    if (t < RPB) lh[t] = 0;
    __syncthreads();
    for (int i = start + t; i < end; i += 1024)
        atomicAdd(&lh[((unsigned)Q[i].x) >> 17], 1);
    __syncthreads();
    int x = (t < RPB) ? lh[t] : 0;
    if (t < RPB) s[t] = x;
    __syncthreads();
    for (int off = 1; off < RPB; off <<= 1) {
        int v = (t >= off && t < RPB) ? s[t - off] : 0;
        __syncthreads();
        if (t < RPB) s[t] += v;
        __syncthreads();
    }
    if (t < RPB) {
        int excl = s[t] - x;
        rp[(b << RSH) + t] = start + excl;
        lstart[t] = excl;
        lh[t] = 0;
    }
    __syncthreads();
    if (cnt <= CAPB) {
        // row-sorted LDS staging (second Q read is L2-resident)
        for (int i = start + t; i < end; i += 1024) {
            int2 el = Q[i];
            int lr = ((unsigned)el.x) >> 17;
            int rank = atomicAdd(&lh[lr], 1);
            stg[lstart[lr] + rank] = make_int2(el.x & 0x1FFFF, el.y);
        }
        __syncthreads();
        for (int p = t; p < cnt; p += 1024)
            P[start + p] = stg[p];
    } else {
        // fallback: direct global scatter (legacy path)
        for (int i = start + t; i < end; i += 1024) {
            int2 el = Q[i];
            int lr = ((unsigned)el.x) >> 17;
            int rank = atomicAdd(&lh[lr], 1);
            P[start + lstart[lr] + rank] = make_int2(el.x & 0x1FFFF, el.y);
        }
    }
}

// 4 rows/wave feat gather: h = b1 + sum v*W1[c], stored fp8 (row*16+gl dword).
__global__ void gather_feat_kernel(const int* rp, const int2* P,
                                   const uint2* w1q, const void* b1,
                                   unsigned* hF8, const int* flags, int N) {
    int bf16 = flags[0];
    int wave = (blockIdx.x * blockDim.x + threadIdx.x) >> 6;
    int lane = threadIdx.x & 63;
    int g = lane >> 4, gl = lane & 15;
    int row = 4 * wave + g;
    int s = 0, e = 0;
    if (row < N) { s = rp[row]; e = rp[row + 1]; }
    float a0 = loadF(b1, (size_t)4 * gl,     bf16);
    float a1 = loadF(b1, (size_t)4 * gl + 1, bf16);
    float a2 = loadF(b1, (size_t)4 * gl + 2, bf16);
    float a3 = loadF(b1, (size_t)4 * gl + 3, bf16);
    const int sb = g << 4;
    for (int base = s; base < e; base += 16) {
        int idx = base + gl;
        int cl = 0; float vl = 0.f;
        if (idx < e) ntload(P, idx, &cl, &vl);
        int cnt = min(16, e - base);
        int j = 0;
        for (; j + 4 <= cnt; j += 4) {
            int   c0 = __shfl(cl, sb + j),     c1 = __shfl(cl, sb + j + 1);
            int   c2 = __shfl(cl, sb + j + 2), c3 = __shfl(cl, sb + j + 3);
            float v0 = __shfl(vl, sb + j),     v1 = __shfl(vl, sb + j + 1);
            float v2 = __shfl(vl, sb + j + 2), v3 = __shfl(vl, sb + j + 3);
            uint2 u0 = w1q[c0 * 16 + gl];
            uint2 u1 = w1q[c1 * 16 + gl];
            uint2 u2 = w1q[c2 * 16 + gl];
            uint2 u3 = w1q[c3 * 16 + gl];
            a0 += v0 * bflo(u0.x); a1 += v0 * bfhi(u0.x);
            a2 += v0 * bflo(u0.y); a3 += v0 * bfhi(u0.y);
            a0 += v1 * bflo(u1.x); a1 += v1 * bfhi(u1.x);
            a2 += v1 * bflo(u1.y); a3 += v1 * bfhi(u1.y);
            a0 += v2 * bflo(u2.x); a1 += v2 * bfhi(u2.x);
            a2 += v2 * bflo(u2.y); a3 += v2 * bfhi(u2.y);
            a0 += v3 * bflo(u3.x); a1 += v3 * bfhi(u3.x);
            a2 += v3 * bflo(u3.y); a3 += v3 * bfhi(u3.y);
        }
        for (; j < cnt; j++) {
            int   c = __shfl(cl, sb + j);
            float v = __shfl(vl, sb + j);
            uint2 u = w1q[c * 16 + gl];
            a0 += v * bflo(u.x); a1 += v * bfhi(u.x);
            a2 += v * bflo(u.y); a3 += v * bfhi(u.y);
        }
    }
    if (row < N) hF8[row * 16 + gl] = fp8pack4(a0, a1, a2, a3);
}

// Merged propagation, NO epilogue: h2 = relu(A @ h), fp8 in / fp8 out.
__global__ void gather_edge_h2_kernel(const int* rp, const int2* P,
                                      const unsigned* hF8, unsigned* h2F8,
                                      int N) {
    int wave = (blockIdx.x * blockDim.x + threadIdx.x) >> 6;
    int lane = threadIdx.x & 63;
    int g = lane >> 4, gl = lane & 15;
    int row = 4 * wave + g;
    int s = 0, e = 0;
    if (row < N) { s = rp[N + row]; e = rp[N + row + 1]; }
    float a0 = 0.f, a1 = 0.f, a2 = 0.f, a3 = 0.f;
    const int sb = g << 4;
    for (int base = s; base < e; base += 16) {
        int idx = base + gl;
        int cl = 0; float wl = 0.f;
        if (idx < e) ntload(P, idx, &cl, &wl);
        int cnt = min(16, e - base);
        int j = 0;
        for (; j + 8 <= cnt; j += 8) {
            int   c0 = __shfl(cl, sb + j),     c1 = __shfl(cl, sb + j + 1);
            int   c2 = __shfl(cl, sb + j + 2), c3 = __shfl(cl, sb + j + 3);
            int   c4 = __shfl(cl, sb + j + 4), c5 = __shfl(cl, sb + j + 5);
            int   c6 = __shfl(cl, sb + j + 6), c7 = __shfl(cl, sb + j + 7);
            float w0 = __shfl(wl, sb + j),     w1 = __shfl(wl, sb + j + 1);
            float w2 = __shfl(wl, sb + j + 2), w3 = __shfl(wl, sb + j + 3);
            float w4 = __shfl(wl, sb + j + 4), w5 = __shfl(wl, sb + j + 5);
            float w6 = __shfl(wl, sb + j + 6), w7 = __shfl(wl, sb + j + 7);
            int u0 = (int)hF8[c0 * 16 + gl];
            int u1 = (int)hF8[c1 * 16 + gl];
            int u2 = (int)hF8[c2 * 16 + gl];
            int u3 = (int)hF8[c3 * 16 + gl];
            int u4 = (int)hF8[c4 * 16 + gl];
            int u5 = (int)hF8[c5 * 16 + gl];
            int u6 = (int)hF8[c6 * 16 + gl];
            int u7 = (int)hF8[c7 * 16 + gl];
            a0 += w0 * __builtin_amdgcn_cvt_f32_fp8(u0, 0);
            a1 += w0 * __builtin_amdgcn_cvt_f32_fp8(u0, 1);
            a2 += w0 * __builtin_amdgcn_cvt_f32_fp8(u0, 2);
            a3 += w0 * __builtin_amdgcn_cvt_f32_fp8(u0, 3);
            a0 += w1 * __builtin_amdgcn_cvt_f32_fp8(u1, 0);
            a1 += w1 * __builtin_amdgcn_cvt_f32_fp8(u1, 1);
            a2 += w1 * __builtin_amdgcn_cvt_f32_fp8(u1, 2);
            a3 += w1 * __builtin_amdgcn_cvt_f32_fp8(u1, 3);
            a0 += w2 * __builtin_amdgcn_cvt_f32_fp8(u2, 0);
            a1 += w2 * __builtin_amdgcn_cvt_f32_fp8(u2, 1);
            a2 += w2 * __builtin_amdgcn_cvt_f32_fp8(u2, 2);
            a3 += w2 * __builtin_amdgcn_cvt_f32_fp8(u2, 3);
            a0 += w3 * __builtin_amdgcn_cvt_f32_fp8(u3, 0);
            a1 += w3 * __builtin_amdgcn_cvt_f32_fp8(u3, 1);
            a2 += w3 * __builtin_amdgcn_cvt_f32_fp8(u3, 2);
            a3 += w3 * __builtin_amdgcn_cvt_f32_fp8(u3, 3);
            a0 += w4 * __builtin_amdgcn_cvt_f32_fp8(u4, 0);
            a1 += w4 * __builtin_amdgcn_cvt_f32_fp8(u4, 1);
            a2 += w4 * __builtin_amdgcn_cvt_f32_fp8(u4, 2);
            a3 += w4 * __builtin_amdgcn_cvt_f32_fp8(u4, 3);
            a0 += w5 * __builtin_amdgcn_cvt_f32_fp8(u5, 0);
            a1 += w5 * __builtin_amdgcn_cvt_f32_fp8(u5, 1);
            a2 += w5 * __builtin_amdgcn_cvt_f32_fp8(u5, 2);
            a3 += w5 * __builtin_amdgcn_cvt_f32_fp8(u5, 3);
            a0 += w6 * __builtin_amdgcn_cvt_f32_fp8(u6, 0);
            a1 += w6 * __builtin_amdgcn_cvt_f32_fp8(u6, 1);
            a2 += w6 * __builtin_amdgcn_cvt_f32_fp8(u6, 2);
            a3 += w6 * __builtin_amdgcn_cvt_f32_fp8(u6, 3);
            a0 += w7 * __builtin_amdgcn_cvt_f32_fp8(u7, 0);
            a1 += w7 * __builtin_amdgcn_cvt_f32_fp8(u7, 1);
            a2 += w7 * __builtin_amdgcn_cvt_f32_fp8(u7, 2);
            a3 += w7 * __builtin_amdgcn_cvt_f32_fp8(u7, 3);
        }
        for (; j < cnt; j++) {
            int   c = __shfl(cl, sb + j);
            float w = __shfl(wl, sb + j);
            int u = (int)hF8[c * 16 + gl];
            a0 += w * __builtin_amdgcn_cvt_f32_fp8(u, 0);
            a1 += w * __builtin_amdgcn_cvt_f32_fp8(u, 1);
            a2 += w * __builtin_amdgcn_cvt_f32_fp8(u, 2);
            a3 += w * __builtin_amdgcn_cvt_f32_fp8(u, 3);
        }
    }
    if (row < N)
        h2F8[row * 16 + gl] = fp8pack4(fmaxf(a0, 0.f), fmaxf(a1, 0.f),
                                       fmaxf(a2, 0.f), fmaxf(a3, 0.f));
}

// Dense via MFMA: z = relu_h2 @ W2 + b2, fp8 out. One wave per 16-row tile.
// A: h2 rows as bf16 (fp8->bf16 exact); B: pre-swizzled W2 frags; bias in C.
__global__ void dense_mfma_kernel(const unsigned* h2F8, const uint4* w2f,
                                  const void* b2, unsigned char* zb,
                                  const int* flags, int N) {
    int bf16 = flags[0];
    int wid  = (int)((blockIdx.x * blockDim.x + threadIdx.x) >> 6);
    int lane = threadIdx.x & 63;
    int ntiles = (N + 15) >> 4;
    if (wid >= ntiles) return;
    const int g = lane >> 4;
    const int fr = lane & 15;

    // A fragments: row = wid*16 + fr, k = kh*32 + g*8 + q
    int arow = wid * 16 + fr;
    const uint2* hrow = (const uint2*)(h2F8 + (size_t)arow * 16);
    short8 af0 = cvt8(hrow[g]);        // kh=0: dwords 2g,2g+1
    short8 af1 = cvt8(hrow[4 + g]);    // kh=1: dwords 8+2g,8+2g+1

    // B fragments + bias-initialized accumulators
    f32x4 acc[3];
#pragma unroll
    for (int t = 0; t < 3; t++) {
        int col = t * 16 + fr;
        float bias = (col < LAB) ? loadF(b2, (size_t)col, bf16) : 0.f;
        acc[t][0] = bias; acc[t][1] = bias; acc[t][2] = bias; acc[t][3] = bias;
        uint4 b0 = w2f[(t * 2 + 0) * 64 + lane];
        uint4 b1 = w2f[(t * 2 + 1) * 64 + lane];
        acc[t] = __builtin_amdgcn_mfma_f32_16x16x32_bf16(
            af0, *(short8*)&b0, acc[t], 0, 0, 0);
        acc[t] = __builtin_amdgcn_mfma_f32_16x16x32_bf16(
            af1, *(short8*)&b1, acc[t], 0, 0, 0);
    }

    // epilogue: D row = wid*16 + g*4 + q, col = t*16 + fr
#pragma unroll
    for (int t = 0; t < 3; t++) {
        int col = t * 16 + fr;
        if (col < LAB) {
#pragma unroll
            for (int q = 0; q < 4; q++) {
                int orow = wid * 16 + g * 4 + q;
                if (orow < N) {
                    int pk = __builtin_amdgcn_cvt_pk_fp8_f32(acc[t][q], acc[t][q], 0, false);
                    zb[(size_t)orow * LAB + col] = (unsigned char)(pk & 0xFF);
                }
            }
        }
    }
}

// 4 rows/wave: z2 = A@z (fp8 gather), fused log_softmax -> out.
__global__ void gather_edge_lsm_kernel(const int* rp, const int2* P,
                                       const unsigned* zF8, void* out,
                                       const int* flags, int N) {
    int bf16 = flags[0];
    int wave = (blockIdx.x * blockDim.x + threadIdx.x) >> 6;
    int lane = threadIdx.x & 63;
    int g = lane >> 4, gl = lane & 15;
    int row = 4 * wave + g;
    int s = 0, e = 0;
    if (row < N) { s = rp[N + row]; e = rp[N + row + 1]; }
    float a0 = 0.f, a1 = 0.f, a2 = 0.f, a3 = 0.f;
    const int sb = g << 4;
    const int act = (gl < 10);
    for (int base = s; base < e; base += 16) {
        int idx = base + gl;
        int cl = 0; float wl = 0.f;
        if (idx < e) ntload(P, idx, &cl, &wl);
        int cnt = min(16, e - base);
        int j = 0;
        for (; j + 4 <= cnt; j += 4) {
            int   c0 = __shfl(cl, sb + j),     c1 = __shfl(cl, sb + j + 1);
            int   c2 = __shfl(cl, sb + j + 2), c3 = __shfl(cl, sb + j + 3);
            float w0 = __shfl(wl, sb + j),     w1 = __shfl(wl, sb + j + 1);
            float w2 = __shfl(wl, sb + j + 2), w3 = __shfl(wl, sb + j + 3);
            if (act) {
                int u0 = (int)zF8[c0 * 10 + gl];
                int u1 = (int)zF8[c1 * 10 + gl];
                int u2 = (int)zF8[c2 * 10 + gl];
                int u3 = (int)zF8[c3 * 10 + gl];
                a0 += w0 * __builtin_amdgcn_cvt_f32_fp8(u0, 0);
                a1 += w0 * __builtin_amdgcn_cvt_f32_fp8(u0, 1);
                a2 += w0 * __builtin_amdgcn_cvt_f32_fp8(u0, 2);
                a3 += w0 * __builtin_amdgcn_cvt_f32_fp8(u0, 3);
                a0 += w1 * __builtin_amdgcn_cvt_f32_fp8(u1, 0);
                a1 += w1 * __builtin_amdgcn_cvt_f32_fp8(u1, 1);
                a2 += w1 * __builtin_amdgcn_cvt_f32_fp8(u1, 2);
                a3 += w1 * __builtin_amdgcn_cvt_f32_fp8(u1, 3);
                a0 += w2 * __builtin_amdgcn_cvt_f32_fp8(u2, 0);
                a1 += w2 * __builtin_amdgcn_cvt_f32_fp8(u2, 1);
                a2 += w2 * __builtin_amdgcn_cvt_f32_fp8(u2, 2);
                a3 += w2 * __builtin_amdgcn_cvt_f32_fp8(u2, 3);
                a0 += w3 * __builtin_amdgcn_cvt_f32_fp8(u3, 0);
                a1 += w3 * __builtin_amdgcn_cvt_f32_fp8(u3, 1);
                a2 += w3 * __builtin_amdgcn_cvt_f32_fp8(u3, 2);
                a3 += w3 * __builtin_amdgcn_cvt_f32_fp8(u3, 3);
            }
        }
        for (; j < cnt; j++) {
            int   c = __shfl(cl, sb + j);
            float w = __shfl(wl, sb + j);
            if (act) {
                int u = (int)zF8[c * 10 + gl];
                a0 += w * __builtin_amdgcn_cvt_f32_fp8(u, 0);
                a1 += w * __builtin_amdgcn_cvt_f32_fp8(u, 1);
                a2 += w * __builtin_amdgcn_cvt_f32_fp8(u, 2);
                a3 += w * __builtin_amdgcn_cvt_f32_fp8(u, 3);
            }
        }
    }
    float m = act ? fmaxf(fmaxf(a0, a1), fmaxf(a2, a3)) : -INFINITY;
#pragma unroll
    for (int off = 8; off; off >>= 1) m = fmaxf(m, __shfl_xor(m, off));
    float es = act ? (__expf(a0 - m) + __expf(a1 - m) + __expf(a2 - m) + __expf(a3 - m)) : 0.f;
#pragma unroll
    for (int off = 8; off; off >>= 1) es += __shfl_xor(es, off);
    float lse = m + __logf(es);
    if (act && row < N) {
        float o0 = a0 - lse, o1 = a1 - lse, o2 = a2 - lse, o3 = a3 - lse;
        if (bf16) {
            ((uint2*)out)[(size_t)row * 10 + gl] =
                make_uint2(bfpack(o0, o1), bfpack(o2, o3));
        } else {
            float4 v = make_float4(o0, o1, o2, o3);
            ((float4*)out)[(size_t)row * 10 + gl] = v;
        }
    }
}

extern "C" void kernel_launch(void* const* d_in, const int* in_sizes, int n_in,
                              void* d_out, int out_size, void* d_ws, size_t ws_size,
                              hipStream_t stream) {
    const void* fidx = d_in[0];
    const void* fval = d_in[1];
    const void* eidx = d_in[2];
    const void* ew   = d_in[3];
    const void* W1   = d_in[4];
    const void* b1   = d_in[5];
    const void* W2   = d_in[6];
    const void* b2   = d_in[7];

    const int nnz = in_sizes[1];          // 2,500,000
    const int nW1 = in_sizes[4];          // 2048*64
    const int nE  = in_sizes[3];          // 1,700,000
    const int N   = out_size / LAB;       // 100,000
    const int M   = 2 * N;
    const int nT  = nnz + nE;
    const int K   = (M + RPB - 1) >> RSH;          // 782 buckets
    const int NBLK = (nT + TILE_A - 1) / TILE_A;   // 684 tile blocks

    auto align256 = [](size_t x) { return (x + 255) & ~(size_t)255; };
    char* ws = (char*)d_ws;
    size_t off = 0;
    int*   flags   = (int*)(ws + off);   off += 256;
    // front: hF8 (6.4MB) | h2F8 (6.4MB) | zF8 (4MB); Q (int2, 33.6MB) overlays
    // front and dies before gather_feat writes hF8.
    char*  front   = ws + off;
    unsigned* hF8  = (unsigned*)front;                       // N*16 dwords
    unsigned* h2F8 = hF8 + (size_t)N * 16;                   // N*16 dwords
    unsigned char* zb = (unsigned char*)(h2F8 + (size_t)N * 16);  // N*40 B
    size_t frontBytes = (size_t)N * (64 + 64 + 40);
    size_t qBytes     = (size_t)nT * 8;
    off += align256(frontBytes > qBytes ? frontBytes : qBytes);
    int2*  P       = (int2*)(ws + off);  off += align256((size_t)nT * 8);
    int*   rp      = (int*)(ws + off);   off += align256(((size_t)KMAX << RSH) * 4 + 16);
    uint2* w1q     = (uint2*)(ws + off); off += align256((size_t)nW1 * 2);
    uint4* w2f     = (uint4*)(ws + off); off += align256((size_t)384 * 16);
    int*   cntB    = (int*)(ws + off);   off += KMAX * 4;
    int*   bqstart = (int*)(ws + off);   off += KMAX * 4;
    int*   cntPB   = (int*)(ws + off);   off += align256((size_t)KMAX * NBLK * 4);
    int2*  Q       = (int2*)front;

    // 1. dtype probe
    probe_kernel<<<1, 64, 0, stream>>>(b1, fidx, flags);

    // 2. zero bucket histogram; stage W1 packed + W2 MFMA fragments
    zero_kernel<<<1, 256, 0, stream>>>((int4*)cntB, KMAX / 4);
    convw1_kernel<<<(nW1 / 4 + 255) / 256, 256, 0, stream>>>(W1, w1q, flags, nW1 / 4);
    convw2_kernel<<<1, 384, 0, stream>>>(W2, w2f, flags);

    // 3. bucket histogram, tiled like bucketA -> per-(bucket,block) counts
    histB_kernel<<<NBLK, 1024, 0, stream>>>(fidx, eidx, cntB, cntPB,
                                            flags, nnz, nE, N, NBLK);

    // 4. bucket scan -> bucket starts
    scanB_kernel<<<1, KMAX, 0, stream>>>(cntB, bqstart, K);

    // 5. per-bucket scan over blocks -> absolute write base per (bucket,block)
    scanPB_kernel<<<K, 1024, 0, stream>>>(cntPB, bqstart, NBLK);

    // 6. pass A: register tile -> LDS bucket-sort -> coalesced scatter into Q
    bucketA_kernel<<<NBLK, 1024, 0, stream>>>(fidx, fval, eidx, ew, flags,
                                              cntPB, Q, nnz, nE, N, NBLK);

    // 7. pass B: per-bucket row sort via LDS staging -> coalesced P + rp
    bucketB_kernel<<<K, 1024, 0, stream>>>(Q, bqstart, rp, P, nT, K);

    // 8. h = sparse_features @ W1 + b1 -> fp8
    int nwaves = (N + 3) / 4;
    int gblocks = (int)(((size_t)nwaves * 64 + 255) / 256);
    gather_feat_kernel<<<gblocks, 256, 0, stream>>>(rp, P, w1q, b1, hF8, flags, N);

    // 9. h2 = relu(A @ h) -> fp8 (gather-only, no epilogue)
    gather_edge_h2_kernel<<<gblocks, 256, 0, stream>>>(rp, P, hF8, h2F8, N);

    // 10. z = h2 @ W2 + b2 -> fp8 via MFMA (one wave per 16-row tile)
    int ntiles = (N + 15) / 16;
    int dblocks = (int)(((size_t)ntiles * 64 + 255) / 256);
    dense_mfma_kernel<<<dblocks, 256, 0, stream>>>(h2F8, w2f, b2, zb, flags, N);

    // 11. out = log_softmax(A @ z)
    gather_edge_lsm_kernel<<<gblocks, 256, 0, stream>>>(rp, P, (const unsigned*)zb,
                                                        d_out, flags, N);
}